// Round 3
// baseline (623.133 us; speedup 1.0000x reference)
//
#include <hip/hip_runtime.h>
#include <math.h>

// Problem constants (C = RC = 1)
#define BB 2
#define SS 1024
#define DD 1024
#define NH 16
#define DH 64
#define MAXN 0.996f   // (1 - PROJ_EPS)/RC

typedef __attribute__((ext_vector_type(8))) short bf16x8;  // MFMA A/B frag (4 VGPRs)
typedef __attribute__((ext_vector_type(4))) float f32x4;   // MFMA C/D frag

__device__ __forceinline__ float xor_sum16(float v){
  v += __shfl_xor(v, 1, 64);
  v += __shfl_xor(v, 2, 64);
  v += __shfl_xor(v, 4, 64);
  v += __shfl_xor(v, 8, 64);
  return v;
}

__device__ __forceinline__ unsigned short f2bf(float x){
  unsigned u = __builtin_bit_cast(unsigned, x);
  unsigned r = u + 0x7FFFu + ((u >> 16) & 1u);   // RNE
  return (unsigned short)(r >> 16);
}
__device__ __forceinline__ float bf2f(unsigned short b){
  unsigned u = ((unsigned)b) << 16;
  return __builtin_bit_cast(float, u);
}

// ---------------- K1a: column norms of z + cosh/sinh(2r) ----------------
__global__ __launch_bounds__(256) void col_stats_kernel(
    const float* __restrict__ zq, const float* __restrict__ zk, const float* __restrict__ zv,
    const float* __restrict__ rq, const float* __restrict__ rk, const float* __restrict__ rv,
    float* __restrict__ zn, float* __restrict__ c2r, float* __restrict__ s2r)
{
  const int m = blockIdx.y;
  const float* z = (m == 0) ? zq : ((m == 1) ? zk : zv);
  const float* r = (m == 0) ? rq : ((m == 1) ? rk : rv);
  const int j = blockIdx.x * 256 + threadIdx.x;   // 0..1023
  float acc = 0.0f;
  for (int i = 0; i < DD; ++i) { float t = z[(size_t)i * DD + j]; acc = fmaf(t, t, acc); }
  float n = fmaxf(sqrtf(acc), 1e-15f);
  zn[m * DD + j] = n;
  float rr = 2.0f * r[j];
  c2r[m * DD + j] = coshf(rr);
  s2r[m * DD + j] = sinhf(rr);
}

// ---------------- K1b: per-row ||x||^2 ----------------
__global__ __launch_bounds__(256) void row_cx2_kernel(const float* __restrict__ x,
                                                      float* __restrict__ cx2)
{
  const int wave = threadIdx.x >> 6;
  const int lane = threadIdx.x & 63;
  const int row = blockIdx.x * 4 + wave;          // 2048 rows, grid 512
  const float* xr = x + (size_t)row * DD;
  float acc = 0.0f;
  for (int i = lane; i < DD; i += 64) { float t = xr[i]; acc = fmaf(t, t, acc); }
  #pragma unroll
  for (int m = 1; m < 64; m <<= 1) acc += __shfl_xor(acc, m, 64);
  if (lane == 0) cx2[row] = acc;
}

// ---------------- K1c: x -> split-bf16 (hi/lo), row-major [m][k] ----------------
__global__ __launch_bounds__(256) void convert_x_kernel(
    const float* __restrict__ x,
    unsigned short* __restrict__ Xhi, unsigned short* __restrict__ Xlo)
{
  const size_t g0 = ((size_t)blockIdx.x * 256 + threadIdx.x) * 8;
  #pragma unroll
  for (int h = 0; h < 2; ++h) {
    float4 v = *(const float4*)(x + g0 + 4 * h);
    float a[4] = {v.x, v.y, v.z, v.w};
    ushort4 hv, lv;
    unsigned short* hp = (unsigned short*)&hv;
    unsigned short* lp = (unsigned short*)&lv;
    #pragma unroll
    for (int j = 0; j < 4; ++j) {
      unsigned short hi = f2bf(a[j]);
      hp[j] = hi;
      lp[j] = f2bf(a[j] - bf2f(hi));
    }
    *(ushort4*)(Xhi + g0 + 4 * h) = hv;
    *(ushort4*)(Xlo + g0 + 4 * h) = lv;
  }
}

// ---------------- K1d: z -> split-bf16 transposed ZT[mat][n][k] ----------------
__global__ __launch_bounds__(256) void convert_zt_kernel(
    const float* __restrict__ zq, const float* __restrict__ zk, const float* __restrict__ zv,
    unsigned short* __restrict__ ZThi, unsigned short* __restrict__ ZTlo)
{
  const int kt = blockIdx.x, nt = blockIdx.y, mat = blockIdx.z;
  const float* z = (mat == 0) ? zq : ((mat == 1) ? zk : zv);
  const int tid = threadIdx.x;
  __shared__ unsigned T[64][69];   // packed (lo<<16)|hi

  #pragma unroll
  for (int i = 0; i < 4; ++i) {
    const int g = tid + 256 * i;
    const int kr = g >> 4, nc = (g & 15) * 4;
    float4 v = *(const float4*)(z + (size_t)(kt * 64 + kr) * DD + nt * 64 + nc);
    float a[4] = {v.x, v.y, v.z, v.w};
    #pragma unroll
    for (int j = 0; j < 4; ++j) {
      unsigned short hi = f2bf(a[j]);
      unsigned short lo = f2bf(a[j] - bf2f(hi));
      T[kr][nc + j] = ((unsigned)lo << 16) | (unsigned)hi;
    }
  }
  __syncthreads();
  #pragma unroll
  for (int i = 0; i < 4; ++i) {
    const int g = tid + 256 * i;
    const int nr = g >> 4, kc = (g & 15) * 4;
    ushort4 hv, lv;
    unsigned short* hp = (unsigned short*)&hv;
    unsigned short* lp = (unsigned short*)&lv;
    #pragma unroll
    for (int j = 0; j < 4; ++j) {
      unsigned u = T[kc + j][nr];
      hp[j] = (unsigned short)(u & 0xFFFFu);
      lp[j] = (unsigned short)(u >> 16);
    }
    const size_t ob = ((size_t)mat * DD + nt * 64 + nr) * DD + kt * 64 + kc;
    *(ushort4*)(ZThi + ob) = hv;
    *(ushort4*)(ZTlo + ob) = lv;
  }
}

// ---------------- K2: split-bf16 MFMA GEMM (x@z) + Poincare-linear epilogue ----------------
// 128x128 tile, K-chunk 32 (one 16x16x32 step), 4 waves: wave w owns rows [32w,32w+32).
// Grid (8 n-tiles, 16 m-tiles, 3 mats): blockIdx.x fastest -> XCD ~ n-tile, pinning the
// 1.5 MB ZT column slab per XCD L2.
__global__ __launch_bounds__(256) void gemm_mfma_kernel(
    const unsigned short* __restrict__ Xhi, const unsigned short* __restrict__ Xlo,
    const unsigned short* __restrict__ ZThi, const unsigned short* __restrict__ ZTlo,
    const float* __restrict__ zn, const float* __restrict__ c2r, const float* __restrict__ s2r,
    const float* __restrict__ cx2,
    float* __restrict__ Q, float* __restrict__ K, float* __restrict__ GV,
    float* __restrict__ q2, float* __restrict__ k2, float* __restrict__ gm1)
{
  constexpr int LDK = 40;                    // halfword stride (80 B = 20 words -> 2-way, free)
  __shared__ unsigned short Xs_hi[128 * LDK], Xs_lo[128 * LDK];
  __shared__ unsigned short Zs_hi[128 * LDK], Zs_lo[128 * LDK];

  const int mat = blockIdx.z;
  float* OutM = (mat == 0) ? Q  : ((mat == 1) ? K  : GV);
  float* Stat = (mat == 0) ? q2 : ((mat == 1) ? k2 : gm1);

  const int n0 = blockIdx.x * 128;
  const int m0 = blockIdx.y * 128;
  const int tid = threadIdx.x;
  const int wave = tid >> 6, lane = tid & 63;
  const int tx = lane & 15, quad = lane >> 4;

  const int sr = tid >> 1, sc = (tid & 1) * 16 + 256;  // unused guard (silence)
  (void)sr; (void)sc;

  f32x4 acc[2][8] = {};

  for (int kt = 0; kt < 32; ++kt) {
    const int k0 = kt * 32;
    __syncthreads();
    #pragma unroll
    for (int i = 0; i < 2; ++i) {
      const int g = tid + 256 * i;           // 0..511
      const int r = g >> 2, c = (g & 3) * 8; // 128 rows x 4 chunks of 8 bf16
      *(uint4*)&Xs_hi[r * LDK + c] = *(const uint4*)(Xhi + (size_t)(m0 + r) * DD + k0 + c);
      *(uint4*)&Xs_lo[r * LDK + c] = *(const uint4*)(Xlo + (size_t)(m0 + r) * DD + k0 + c);
      *(uint4*)&Zs_hi[r * LDK + c] = *(const uint4*)(ZThi + ((size_t)mat * DD + n0 + r) * DD + k0 + c);
      *(uint4*)&Zs_lo[r * LDK + c] = *(const uint4*)(ZTlo + ((size_t)mat * DD + n0 + r) * DD + k0 + c);
    }
    __syncthreads();

    bf16x8 a_h[2], a_l[2];
    #pragma unroll
    for (int mb = 0; mb < 2; ++mb) {
      const int row = 32 * wave + 16 * mb + tx;
      a_h[mb] = *(const bf16x8*)&Xs_hi[row * LDK + 8 * quad];
      a_l[mb] = *(const bf16x8*)&Xs_lo[row * LDK + 8 * quad];
    }
    #pragma unroll
    for (int nb = 0; nb < 8; ++nb) {
      bf16x8 b_h = *(const bf16x8*)&Zs_hi[(16 * nb + tx) * LDK + 8 * quad];
      bf16x8 b_l = *(const bf16x8*)&Zs_lo[(16 * nb + tx) * LDK + 8 * quad];
      #pragma unroll
      for (int mb = 0; mb < 2; ++mb) {
        acc[mb][nb] = __builtin_amdgcn_mfma_f32_16x16x32_bf16(a_h[mb], b_h, acc[mb][nb], 0, 0, 0);
        acc[mb][nb] = __builtin_amdgcn_mfma_f32_16x16x32_bf16(a_h[mb], b_l, acc[mb][nb], 0, 0, 0);
        acc[mb][nb] = __builtin_amdgcn_mfma_f32_16x16x32_bf16(a_l[mb], b_h, acc[mb][nb], 0, 0, 0);
      }
    }
  }

  // per-col params (8 cols per lane)
  float znv[8], c2v[8], s2v[8];
  #pragma unroll
  for (int nb = 0; nb < 8; ++nb) {
    const int col = mat * DD + n0 + 16 * nb + tx;
    znv[nb] = zn[col]; c2v[nb] = c2r[col]; s2v[nb] = s2r[col];
  }

  // Epilogue. C/D layout: col = tx, row = 4*quad + reg.
  #pragma unroll
  for (int mb = 0; mb < 2; ++mb) {
    #pragma unroll
    for (int r = 0; r < 4; ++r) {
      const int row = m0 + 32 * wave + 16 * mb + 4 * quad + r;
      const float c2 = cx2[row];
      const float inv = 1.0f / fmaxf(1.0f - c2, 1e-15f);
      const float onec = 1.0f + c2;
      float y[8];
      #pragma unroll
      for (int nb = 0; nb < 8; ++nb) {
        const float u = (2.0f * (acc[mb][nb][r] / znv[nb]) * c2v[nb] - onec * s2v[nb]) * inv;
        const float w = 2.0f * znv[nb] * asinhf(u);
        y[nb] = sinhf(w);
      }
      const int b = row >> 10, s = row & 1023;
      #pragma unroll
      for (int hg = 0; hg < 2; ++hg) {       // two heads per 128-col tile
        float n2 = 0.f;
        #pragma unroll
        for (int j = 0; j < 4; ++j) n2 = fmaf(y[4*hg+j], y[4*hg+j], n2);
        n2 = xor_sum16(n2);
        float n = fmaxf(sqrtf(n2), 1e-15f);
        float s1 = (n > MAXN) ? (MAXN / n) : 1.0f;      // project #1
        n2 = n2 * s1 * s1;
        float f = 1.0f / (1.0f + sqrtf(1.0f + n2));     // exp-map scaling
        float fs = s1 * f;
        n2 = n2 * f * f;
        float nb2 = fmaxf(sqrtf(n2), 1e-15f);
        float s2f = (nb2 > MAXN) ? (MAXN / nb2) : 1.0f; // project #2
        fs *= s2f;
        n2 = n2 * s2f * s2f;

        const int head = blockIdx.x * 2 + hg;
        const size_t bh = (size_t)(b * NH + head);
        const size_t outbase = (bh * SS + s) * DH;
        if (mat == 2) {
          const float gamma = 2.0f / fmaxf(1.0f - n2, 1e-15f);
          #pragma unroll
          for (int j = 0; j < 4; ++j)
            OutM[outbase + 16 * j + tx] = y[4*hg+j] * fs * gamma;
          if (tx == 0) Stat[bh * SS + s] = gamma - 1.0f;
        } else {
          #pragma unroll
          for (int j = 0; j < 4; ++j)
            OutM[outbase + 16 * j + tx] = y[4*hg+j] * fs;
          if (tx == 0) Stat[bh * SS + s] = n2;
        }
      }
    }
  }
}

// ---------------- K3: fp32 -> split-bf16 (hi/lo) convert; GV also transposed ----------------
__global__ __launch_bounds__(256) void convert_kernel(
    const float* __restrict__ QKV,   // Q,K,GV contiguous, each [bh][s][dh]
    unsigned short* __restrict__ Qhi, unsigned short* __restrict__ Qlo,
    unsigned short* __restrict__ Khi, unsigned short* __restrict__ Klo,
    unsigned short* __restrict__ GThi, unsigned short* __restrict__ GTlo)
{
  const int st = blockIdx.x, bh = blockIdx.y, mat = blockIdx.z;
  const int tid = threadIdx.x;
  const size_t nQKV = (size_t)BB * NH * SS * DH;
  const float* src = QKV + (size_t)mat * nQKV + ((size_t)bh * SS + st * 64) * DH;
  __shared__ unsigned T[64][69];   // packed (lo<<16)|hi, padded stride

  if (mat < 2) {
    unsigned short* dh_ = ((mat == 0) ? Qhi : Khi) + ((size_t)bh * SS + st * 64) * DH;
    unsigned short* dl_ = ((mat == 0) ? Qlo : Klo) + ((size_t)bh * SS + st * 64) * DH;
    #pragma unroll
    for (int i = 0; i < 4; ++i) {
      const int g = tid + 256 * i;
      const int row = g >> 4, c4 = (g & 15) * 4;
      float4 v = *(const float4*)(src + row * DH + c4);
      float a[4] = {v.x, v.y, v.z, v.w};
      ushort4 hv, lv;
      unsigned short* hp = (unsigned short*)&hv;
      unsigned short* lp = (unsigned short*)&lv;
      #pragma unroll
      for (int j = 0; j < 4; ++j) {
        unsigned short hi = f2bf(a[j]);
        hp[j] = hi;
        lp[j] = f2bf(a[j] - bf2f(hi));
      }
      *(ushort4*)(dh_ + row * DH + c4) = hv;
      *(ushort4*)(dl_ + row * DH + c4) = lv;
    }
  } else {
    #pragma unroll
    for (int i = 0; i < 4; ++i) {
      const int g = tid + 256 * i;
      const int row = g >> 4, c4 = (g & 15) * 4;
      float4 v = *(const float4*)(src + row * DH + c4);
      float a[4] = {v.x, v.y, v.z, v.w};
      #pragma unroll
      for (int j = 0; j < 4; ++j) {
        unsigned short hi = f2bf(a[j]);
        unsigned short lo = f2bf(a[j] - bf2f(hi));
        T[row][c4 + j] = ((unsigned)lo << 16) | (unsigned)hi;
      }
    }
    __syncthreads();
    #pragma unroll
    for (int i = 0; i < 4; ++i) {
      const int g = tid + 256 * i;
      const int kb = g & 15, dhr = g >> 4;
      ushort4 hv, lv;
      unsigned short* hp = (unsigned short*)&hv;
      unsigned short* lp = (unsigned short*)&lv;
      #pragma unroll
      for (int j = 0; j < 4; ++j) {
        unsigned u = T[4 * kb + j][dhr];
        hp[j] = (unsigned short)(u & 0xFFFFu);
        lp[j] = (unsigned short)(u >> 16);
      }
      const size_t ob = ((size_t)bh * DH + dhr) * SS + st * 64 + 4 * kb;
      *(ushort4*)(GThi + ob) = hv;
      *(ushort4*)(GTlo + ob) = lv;
    }
  }
}

// ---------------- K4: MFMA flash-style hyperbolic attention ----------------
__global__ __launch_bounds__(256) void flash_attn_kernel(
    const unsigned short* __restrict__ Qhi, const unsigned short* __restrict__ Qlo,
    const unsigned short* __restrict__ Khi, const unsigned short* __restrict__ Klo,
    const unsigned short* __restrict__ GThi, const unsigned short* __restrict__ GTlo,
    const float* __restrict__ q2a, const float* __restrict__ k2a, const float* __restrict__ gm1a,
    const float* __restrict__ mask, float* __restrict__ out)
{
  constexpr int LDK = 72;
  __shared__ unsigned short Ks_hi[64 * LDK];
  __shared__ unsigned short Ks_lo[64 * LDK];
  __shared__ unsigned short Gs_hi[64 * LDK];
  __shared__ unsigned short Gs_lo[64 * LDK];
  __shared__ float k2s[64], ik2s[64], gm1s[64], ems[64];

  const int qt = blockIdx.x, h = blockIdx.y, b = blockIdx.z;
  const int bh = b * NH + h;
  const int tid = threadIdx.x;
  const int wave = tid >> 6, lane = tid & 63;
  const int tx = lane & 15, quad = lane >> 4;
  const int r0 = qt * 64;

  bf16x8 qa_h[2], qa_l[2];
  {
    const size_t qoff = ((size_t)bh * SS + r0 + 16 * wave + tx) * DH;
    #pragma unroll
    for (int kc = 0; kc < 2; ++kc) {
      qa_h[kc] = *(const bf16x8*)(Qhi + qoff + 32 * kc + 8 * quad);
      qa_l[kc] = *(const bf16x8*)(Qlo + qoff + 32 * kc + 8 * quad);
    }
  }
  float q2r[4], iq2[4];
  #pragma unroll
  for (int r = 0; r < 4; ++r) {
    q2r[r] = q2a[(size_t)bh * SS + r0 + 16 * wave + 4 * quad + r];
    iq2[r] = 2.0f / fmaxf(1.0f - q2r[r], 1e-15f);
  }

  const f32x4 zero4 = {0.f, 0.f, 0.f, 0.f};
  f32x4 oacc[4] = {zero4, zero4, zero4, zero4};
  float dden[4] = {0.f, 0.f, 0.f, 0.f};

  const int c0 = tid, c1 = tid + 256;
  const int sr0 = c0 >> 3, sc0 = (c0 & 7) * 8;
  const int sr1 = c1 >> 3, sc1 = (c1 & 7) * 8;

  for (int kt = 0; kt < 16; ++kt) {
    const int t0 = kt * 64;
    __syncthreads();
    {
      const size_t kb_ = ((size_t)bh * SS + t0) * DH;
      const size_t gb_ = (size_t)bh * DH * SS + t0;
      *(uint4*)&Ks_hi[sr0 * LDK + sc0] = *(const uint4*)(Khi + kb_ + (size_t)sr0 * DH + sc0);
      *(uint4*)&Ks_hi[sr1 * LDK + sc1] = *(const uint4*)(Khi + kb_ + (size_t)sr1 * DH + sc1);
      *(uint4*)&Ks_lo[sr0 * LDK + sc0] = *(const uint4*)(Klo + kb_ + (size_t)sr0 * DH + sc0);
      *(uint4*)&Ks_lo[sr1 * LDK + sc1] = *(const uint4*)(Klo + kb_ + (size_t)sr1 * DH + sc1);
      *(uint4*)&Gs_hi[sr0 * LDK + sc0] = *(const uint4*)(GThi + gb_ + (size_t)sr0 * SS + sc0);
      *(uint4*)&Gs_hi[sr1 * LDK + sc1] = *(const uint4*)(GThi + gb_ + (size_t)sr1 * SS + sc1);
      *(uint4*)&Gs_lo[sr0 * LDK + sc0] = *(const uint4*)(GTlo + gb_ + (size_t)sr0 * SS + sc0);
      *(uint4*)&Gs_lo[sr1 * LDK + sc1] = *(const uint4*)(GTlo + gb_ + (size_t)sr1 * SS + sc1);
      if (tid < 64) {
        float k2v = k2a[(size_t)bh * SS + t0 + tid];
        k2s[tid] = k2v;
        ik2s[tid] = 1.0f / fmaxf(1.0f - k2v, 1e-15f);
        gm1s[tid] = gm1a[(size_t)bh * SS + t0 + tid];
        ems[tid] = __expf(mask[(size_t)b * SS + t0 + tid]);
      }
    }
    __syncthreads();

    f32x4 sacc[4] = {zero4, zero4, zero4, zero4};
    #pragma unroll
    for (int kc = 0; kc < 2; ++kc) {
      const int ko = 32 * kc + 8 * quad;
      #pragma unroll
      for (int nb = 0; nb < 4; ++nb) {
        bf16x8 kh = *(const bf16x8*)&Ks_hi[(16 * nb + tx) * LDK + ko];
        bf16x8 kl = *(const bf16x8*)&Ks_lo[(16 * nb + tx) * LDK + ko];
        sacc[nb] = __builtin_amdgcn_mfma_f32_16x16x32_bf16(qa_h[kc], kh, sacc[nb], 0, 0, 0);
        sacc[nb] = __builtin_amdgcn_mfma_f32_16x16x32_bf16(qa_h[kc], kl, sacc[nb], 0, 0, 0);
        sacc[nb] = __builtin_amdgcn_mfma_f32_16x16x32_bf16(qa_l[kc], kh, sacc[nb], 0, 0, 0);
      }
    }

    float pb[4][4];
    #pragma unroll
    for (int nb = 0; nb < 4; ++nb) {
      const int key = 16 * nb + tx;
      const float k2v = k2s[key], ikv = ik2s[key], emv = ems[key], gmv = gm1s[key];
      #pragma unroll
      for (int r = 0; r < 4; ++r) {
        float sv = sacc[nb][r];
        float num = fmaxf(fmaf(-2.0f, sv, q2r[r] + k2v), 1e-15f);
        float e = num * iq2[r] * ikv;
        float g = fmaf(e, e, e + e);
        float z = 1.0f + e + __builtin_amdgcn_sqrtf(g);
        float w = emv * __builtin_amdgcn_rcpf(z);
        pb[r][nb] = w;
        dden[r] = fmaf(w, gmv, dden[r]);
      }
    }
    __syncthreads();

    #pragma unroll
    for (int r = 0; r < 4; ++r) {
      const int prow = 16 * wave + 4 * quad + r;
      #pragma unroll
      for (int nb = 0; nb < 4; ++nb) {
        float w = pb[r][nb];
        unsigned short hi = f2bf(w);
        unsigned short lo = f2bf(w - bf2f(hi));
        Ks_hi[prow * LDK + 16 * nb + tx] = hi;
        Ks_lo[prow * LDK + 16 * nb + tx] = lo;
      }
    }
    #pragma unroll
    for (int kc = 0; kc < 2; ++kc) {
      const int ko = 32 * kc + 8 * quad;
      bf16x8 ph = *(const bf16x8*)&Ks_hi[(16 * wave + tx) * LDK + ko];
      bf16x8 pl = *(const bf16x8*)&Ks_lo[(16 * wave + tx) * LDK + ko];
      #pragma unroll
      for (int nb = 0; nb < 4; ++nb) {
        bf16x8 gh = *(const bf16x8*)&Gs_hi[(16 * nb + tx) * LDK + ko];
        bf16x8 gl = *(const bf16x8*)&Gs_lo[(16 * nb + tx) * LDK + ko];
        oacc[nb] = __builtin_amdgcn_mfma_f32_16x16x32_bf16(ph, gh, oacc[nb], 0, 0, 0);
        oacc[nb] = __builtin_amdgcn_mfma_f32_16x16x32_bf16(ph, gl, oacc[nb], 0, 0, 0);
        oacc[nb] = __builtin_amdgcn_mfma_f32_16x16x32_bf16(pl, gh, oacc[nb], 0, 0, 0);
      }
    }
  }

  #pragma unroll
  for (int r = 0; r < 4; ++r) {
    float d = fmaxf(xor_sum16(dden[r]), 1e-10f);
    float invd = 1.0f / d;
    float tm[4]; float sq = 0.f;
    #pragma unroll
    for (int nb = 0; nb < 4; ++nb) { tm[nb] = oacc[nb][r] * invd; sq = fmaf(tm[nb], tm[nb], sq); }
    sq = xor_sum16(sq);
    const float f = 1.0f / (1.0f + sqrtf(fmaxf(1.0f - sq, 1e-15f)));
    const float n2 = sq * f * f;
    const float n = fmaxf(sqrtf(n2), 1e-15f);
    const float s2 = (n > MAXN) ? (MAXN / n) : 1.0f;
    const float fs = f * s2;
    const int qrow = r0 + 16 * wave + 4 * quad + r;
    #pragma unroll
    for (int nb = 0; nb < 4; ++nb)
      out[((size_t)(b * SS + qrow)) * DD + h * DH + 16 * nb + tx] = tm[nb] * fs;
  }
}

// ---------------- host ----------------
extern "C" void kernel_launch(void* const* d_in, const int* in_sizes, int n_in,
                              void* d_out, int out_size, void* d_ws, size_t ws_size,
                              hipStream_t stream) {
  const float* hs   = (const float*)d_in[0];
  const float* mask = (const float*)d_in[1];
  const float* qz   = (const float*)d_in[2];
  const float* qr   = (const float*)d_in[3];
  const float* kz   = (const float*)d_in[4];
  const float* kr   = (const float*)d_in[5];
  const float* vz   = (const float*)d_in[6];
  const float* vr   = (const float*)d_in[7];
  float* out = (float*)d_out;

  float* ws = (float*)d_ws;
  const size_t nQKV = (size_t)BB * NH * SS * DH;   // 2,097,152
  const size_t nStat = (size_t)BB * NH * SS;       // 32,768
  float* Q   = ws;                   // Q,K,GV must stay contiguous (convert_kernel)
  float* K   = Q + nQKV;
  float* GV  = K + nQKV;
  float* q2  = GV + nQKV;
  float* k2  = q2 + nStat;
  float* gm1 = k2 + nStat;
  float* zn  = gm1 + nStat;          // 3*1024
  float* c2r = zn + 3 * DD;
  float* s2r = c2r + 3 * DD;
  float* cx2 = s2r + 3 * DD;         // 2048
  unsigned short* bbuf = (unsigned short*)(cx2 + 2048);  // 16B-aligned
  unsigned short* Qhi  = bbuf;
  unsigned short* Qlo  = Qhi  + nQKV;
  unsigned short* Khi  = Qlo  + nQKV;
  unsigned short* Klo  = Khi  + nQKV;
  unsigned short* GThi = Klo  + nQKV;
  unsigned short* GTlo = GThi + nQKV;

  // X/ZT split-bf16 buffers alias bbuf: live only BEFORE convert_kernel writes bbuf.
  const size_t nX = (size_t)BB * SS * DD;          // 2,097,152
  const size_t nZ = (size_t)3 * DD * DD;           // 3,145,728
  unsigned short* Xhi  = bbuf;
  unsigned short* Xlo  = Xhi + nX;
  unsigned short* ZThi = Xlo + nX;
  unsigned short* ZTlo = ZThi + nZ;                // total 10.5M shorts <= 12.6M (bbuf)

  col_stats_kernel<<<dim3(4, 3), 256, 0, stream>>>(qz, kz, vz, qr, kr, vr, zn, c2r, s2r);
  row_cx2_kernel<<<dim3(512), 256, 0, stream>>>(hs, cx2);
  convert_x_kernel<<<dim3(1024), 256, 0, stream>>>(hs, Xhi, Xlo);
  convert_zt_kernel<<<dim3(16, 16, 3), 256, 0, stream>>>(qz, kz, vz, ZThi, ZTlo);
  gemm_mfma_kernel<<<dim3(8, 16, 3), 256, 0, stream>>>(
      Xhi, Xlo, ZThi, ZTlo, zn, c2r, s2r, cx2, Q, K, GV, q2, k2, gm1);
  convert_kernel<<<dim3(16, BB * NH, 3), 256, 0, stream>>>(
      Q, Qhi, Qlo, Khi, Klo, GThi, GTlo);
  flash_attn_kernel<<<dim3(16, NH, BB), 256, 0, stream>>>(
      Qhi, Qlo, Khi, Klo, GThi, GTlo, q2, k2, gm1, mask, out);
}

// Round 4
// 546.166 us; speedup vs baseline: 1.1409x; 1.1409x over previous
//
#include <hip/hip_runtime.h>
#include <math.h>

// Problem constants (C = RC = 1)
#define BB 2
#define SS 1024
#define DD 1024
#define NH 16
#define DH 64
#define MAXN 0.996f   // (1 - PROJ_EPS)/RC

typedef __attribute__((ext_vector_type(8))) short bf16x8;  // MFMA A/B frag (4 VGPRs)
typedef __attribute__((ext_vector_type(4))) float f32x4;   // MFMA C/D frag

__device__ __forceinline__ float xor_sum16(float v){
  v += __shfl_xor(v, 1, 64);
  v += __shfl_xor(v, 2, 64);
  v += __shfl_xor(v, 4, 64);
  v += __shfl_xor(v, 8, 64);
  return v;
}

__device__ __forceinline__ unsigned short f2bf(float x){
  unsigned u = __builtin_bit_cast(unsigned, x);
  unsigned r = u + 0x7FFFu + ((u >> 16) & 1u);   // RNE
  return (unsigned short)(r >> 16);
}
__device__ __forceinline__ float bf2f(unsigned short b){
  unsigned u = ((unsigned)b) << 16;
  return __builtin_bit_cast(float, u);
}

// ---------------- K1a: column norms of z + cosh/sinh(2r) ----------------
__global__ __launch_bounds__(256) void col_stats_kernel(
    const float* __restrict__ zq, const float* __restrict__ zk, const float* __restrict__ zv,
    const float* __restrict__ rq, const float* __restrict__ rk, const float* __restrict__ rv,
    float* __restrict__ zn, float* __restrict__ c2r, float* __restrict__ s2r)
{
  const int m = blockIdx.y;
  const float* z = (m == 0) ? zq : ((m == 1) ? zk : zv);
  const float* r = (m == 0) ? rq : ((m == 1) ? rk : rv);
  const int j = blockIdx.x * 256 + threadIdx.x;   // 0..1023
  float acc = 0.0f;
  for (int i = 0; i < DD; ++i) { float t = z[(size_t)i * DD + j]; acc = fmaf(t, t, acc); }
  float n = fmaxf(sqrtf(acc), 1e-15f);
  zn[m * DD + j] = n;
  float rr = 2.0f * r[j];
  c2r[m * DD + j] = coshf(rr);
  s2r[m * DD + j] = sinhf(rr);
}

// ---------------- K1b: per-row ||x||^2 ----------------
__global__ __launch_bounds__(256) void row_cx2_kernel(const float* __restrict__ x,
                                                      float* __restrict__ cx2)
{
  const int wave = threadIdx.x >> 6;
  const int lane = threadIdx.x & 63;
  const int row = blockIdx.x * 4 + wave;          // 2048 rows, grid 512
  const float* xr = x + (size_t)row * DD;
  float acc = 0.0f;
  for (int i = lane; i < DD; i += 64) { float t = xr[i]; acc = fmaf(t, t, acc); }
  #pragma unroll
  for (int m = 1; m < 64; m <<= 1) acc += __shfl_xor(acc, m, 64);
  if (lane == 0) cx2[row] = acc;
}

// ---------------- K1c: x -> split-bf16 (hi/lo), row-major [m][k] ----------------
__global__ __launch_bounds__(256) void convert_x_kernel(
    const float* __restrict__ x,
    unsigned short* __restrict__ Xhi, unsigned short* __restrict__ Xlo)
{
  const size_t g0 = ((size_t)blockIdx.x * 256 + threadIdx.x) * 8;
  #pragma unroll
  for (int h = 0; h < 2; ++h) {
    float4 v = *(const float4*)(x + g0 + 4 * h);
    float a[4] = {v.x, v.y, v.z, v.w};
    ushort4 hv, lv;
    unsigned short* hp = (unsigned short*)&hv;
    unsigned short* lp = (unsigned short*)&lv;
    #pragma unroll
    for (int j = 0; j < 4; ++j) {
      unsigned short hi = f2bf(a[j]);
      hp[j] = hi;
      lp[j] = f2bf(a[j] - bf2f(hi));
    }
    *(ushort4*)(Xhi + g0 + 4 * h) = hv;
    *(ushort4*)(Xlo + g0 + 4 * h) = lv;
  }
}

// ---------------- K1d: z -> split-bf16 transposed ZT[mat][n][k] ----------------
__global__ __launch_bounds__(256) void convert_zt_kernel(
    const float* __restrict__ zq, const float* __restrict__ zk, const float* __restrict__ zv,
    unsigned short* __restrict__ ZThi, unsigned short* __restrict__ ZTlo)
{
  const int kt = blockIdx.x, nt = blockIdx.y, mat = blockIdx.z;
  const float* z = (mat == 0) ? zq : ((mat == 1) ? zk : zv);
  const int tid = threadIdx.x;
  __shared__ unsigned T[64][69];   // packed (lo<<16)|hi

  #pragma unroll
  for (int i = 0; i < 4; ++i) {
    const int g = tid + 256 * i;
    const int kr = g >> 4, nc = (g & 15) * 4;
    float4 v = *(const float4*)(z + (size_t)(kt * 64 + kr) * DD + nt * 64 + nc);
    float a[4] = {v.x, v.y, v.z, v.w};
    #pragma unroll
    for (int j = 0; j < 4; ++j) {
      unsigned short hi = f2bf(a[j]);
      unsigned short lo = f2bf(a[j] - bf2f(hi));
      T[kr][nc + j] = ((unsigned)lo << 16) | (unsigned)hi;
    }
  }
  __syncthreads();
  #pragma unroll
  for (int i = 0; i < 4; ++i) {
    const int g = tid + 256 * i;
    const int nr = g >> 4, kc = (g & 15) * 4;
    ushort4 hv, lv;
    unsigned short* hp = (unsigned short*)&hv;
    unsigned short* lp = (unsigned short*)&lv;
    #pragma unroll
    for (int j = 0; j < 4; ++j) {
      unsigned u = T[kc + j][nr];
      hp[j] = (unsigned short)(u & 0xFFFFu);
      lp[j] = (unsigned short)(u >> 16);
    }
    const size_t ob = ((size_t)mat * DD + nt * 64 + nr) * DD + kt * 64 + kc;
    *(ushort4*)(ZThi + ob) = hv;
    *(ushort4*)(ZTlo + ob) = lv;
  }
}

// ---------------- K2: split-bf16 MFMA GEMM (x@z) + Poincare-linear epilogue ----------------
// 128x128 tile, K-chunk 32, 4 waves (wave w owns rows [32w,32w+32)).
// __launch_bounds__(256, 2): 2 waves/EU min -> 256-VGPR budget. Without this the
// backend's LDS-derived occupancy target (4 waves/EU -> 128 VGPR) spilled the
// 64-reg accumulator to scratch every k-iter: 820 MB HBM writes, 453 us (round 3).
__global__ __launch_bounds__(256, 2) void gemm_mfma_kernel(
    const unsigned short* __restrict__ Xhi, const unsigned short* __restrict__ Xlo,
    const unsigned short* __restrict__ ZThi, const unsigned short* __restrict__ ZTlo,
    const float* __restrict__ zn, const float* __restrict__ c2r, const float* __restrict__ s2r,
    const float* __restrict__ cx2,
    float* __restrict__ Q, float* __restrict__ K, float* __restrict__ GV,
    float* __restrict__ q2, float* __restrict__ k2, float* __restrict__ gm1)
{
  constexpr int LDK = 40;                    // halfword stride (80 B) -> ~2-way on frag reads, free
  __shared__ unsigned short Xs_hi[128 * LDK], Xs_lo[128 * LDK];
  __shared__ unsigned short Zs_hi[128 * LDK], Zs_lo[128 * LDK];

  const int mat = blockIdx.z;
  float* OutM = (mat == 0) ? Q  : ((mat == 1) ? K  : GV);
  float* Stat = (mat == 0) ? q2 : ((mat == 1) ? k2 : gm1);

  const int n0 = blockIdx.x * 128;
  const int m0 = blockIdx.y * 128;
  const int tid = threadIdx.x;
  const int wave = tid >> 6, lane = tid & 63;
  const int tx = lane & 15, quad = lane >> 4;

  // staging mapping: 512 slots of (row, 8-halfword chunk)
  const int r_a = tid >> 2,         c_a = (tid & 3) * 8;
  const int r_b = (tid + 256) >> 2, c_b = ((tid + 256) & 3) * 8;

  f32x4 acc[2][8] = {};

  const unsigned short* Xh = Xhi + (size_t)m0 * DD;
  const unsigned short* Xl = Xlo + (size_t)m0 * DD;
  const unsigned short* Zh = ZThi + ((size_t)mat * DD + n0) * DD;
  const unsigned short* Zl = ZTlo + ((size_t)mat * DD + n0) * DD;

  for (int kt = 0; kt < 32; ++kt) {
    const int k0 = kt * 32;
    __syncthreads();
    {
      uint4 xa_h = *(const uint4*)(Xh + (size_t)r_a * DD + k0 + c_a);
      uint4 xb_h = *(const uint4*)(Xh + (size_t)r_b * DD + k0 + c_b);
      uint4 xa_l = *(const uint4*)(Xl + (size_t)r_a * DD + k0 + c_a);
      uint4 xb_l = *(const uint4*)(Xl + (size_t)r_b * DD + k0 + c_b);
      *(uint4*)&Xs_hi[r_a * LDK + c_a] = xa_h;
      *(uint4*)&Xs_hi[r_b * LDK + c_b] = xb_h;
      *(uint4*)&Xs_lo[r_a * LDK + c_a] = xa_l;
      *(uint4*)&Xs_lo[r_b * LDK + c_b] = xb_l;
      uint4 za_h = *(const uint4*)(Zh + (size_t)r_a * DD + k0 + c_a);
      uint4 zb_h = *(const uint4*)(Zh + (size_t)r_b * DD + k0 + c_b);
      uint4 za_l = *(const uint4*)(Zl + (size_t)r_a * DD + k0 + c_a);
      uint4 zb_l = *(const uint4*)(Zl + (size_t)r_b * DD + k0 + c_b);
      *(uint4*)&Zs_hi[r_a * LDK + c_a] = za_h;
      *(uint4*)&Zs_hi[r_b * LDK + c_b] = zb_h;
      *(uint4*)&Zs_lo[r_a * LDK + c_a] = za_l;
      *(uint4*)&Zs_lo[r_b * LDK + c_b] = zb_l;
    }
    __syncthreads();

    bf16x8 a_h[2], a_l[2];
    #pragma unroll
    for (int mb = 0; mb < 2; ++mb) {
      const int row = 32 * wave + 16 * mb + tx;
      a_h[mb] = *(const bf16x8*)&Xs_hi[row * LDK + 8 * quad];
      a_l[mb] = *(const bf16x8*)&Xs_lo[row * LDK + 8 * quad];
    }
    #pragma unroll
    for (int nb = 0; nb < 8; ++nb) {
      bf16x8 b_h = *(const bf16x8*)&Zs_hi[(16 * nb + tx) * LDK + 8 * quad];
      bf16x8 b_l = *(const bf16x8*)&Zs_lo[(16 * nb + tx) * LDK + 8 * quad];
      #pragma unroll
      for (int mb = 0; mb < 2; ++mb) {
        acc[mb][nb] = __builtin_amdgcn_mfma_f32_16x16x32_bf16(a_h[mb], b_h, acc[mb][nb], 0, 0, 0);
        acc[mb][nb] = __builtin_amdgcn_mfma_f32_16x16x32_bf16(a_h[mb], b_l, acc[mb][nb], 0, 0, 0);
        acc[mb][nb] = __builtin_amdgcn_mfma_f32_16x16x32_bf16(a_l[mb], b_h, acc[mb][nb], 0, 0, 0);
      }
    }
  }

  // Epilogue. C/D layout: col = tx, row = 4*quad + reg.
  #pragma unroll
  for (int mb = 0; mb < 2; ++mb) {
    #pragma unroll
    for (int r = 0; r < 4; ++r) {
      const int row = m0 + 32 * wave + 16 * mb + 4 * quad + r;
      const float c2 = cx2[row];
      const float inv = 1.0f / fmaxf(1.0f - c2, 1e-15f);
      const float onec = 1.0f + c2;
      float y[8];
      #pragma unroll
      for (int nb = 0; nb < 8; ++nb) {
        const int col = mat * DD + n0 + 16 * nb + tx;
        const float znv = zn[col];
        const float u = (2.0f * (acc[mb][nb][r] / znv) * c2r[col] - onec * s2r[col]) * inv;
        const float w = 2.0f * znv * asinhf(u);
        y[nb] = sinhf(w);
      }
      const int b = row >> 10, s = row & 1023;
      #pragma unroll
      for (int hg = 0; hg < 2; ++hg) {       // two heads per 128-col tile
        float n2 = 0.f;
        #pragma unroll
        for (int j = 0; j < 4; ++j) n2 = fmaf(y[4*hg+j], y[4*hg+j], n2);
        n2 = xor_sum16(n2);
        float n = fmaxf(sqrtf(n2), 1e-15f);
        float s1 = (n > MAXN) ? (MAXN / n) : 1.0f;      // project #1
        n2 = n2 * s1 * s1;
        float f = 1.0f / (1.0f + sqrtf(1.0f + n2));     // exp-map scaling
        float fs = s1 * f;
        n2 = n2 * f * f;
        float nb2 = fmaxf(sqrtf(n2), 1e-15f);
        float s2f = (nb2 > MAXN) ? (MAXN / nb2) : 1.0f; // project #2
        fs *= s2f;
        n2 = n2 * s2f * s2f;

        const int head = blockIdx.x * 2 + hg;
        const size_t bh = (size_t)(b * NH + head);
        const size_t outbase = (bh * SS + s) * DH;
        if (mat == 2) {
          const float gamma = 2.0f / fmaxf(1.0f - n2, 1e-15f);
          #pragma unroll
          for (int j = 0; j < 4; ++j)
            OutM[outbase + 16 * j + tx] = y[4*hg+j] * fs * gamma;
          if (tx == 0) Stat[bh * SS + s] = gamma - 1.0f;
        } else {
          #pragma unroll
          for (int j = 0; j < 4; ++j)
            OutM[outbase + 16 * j + tx] = y[4*hg+j] * fs;
          if (tx == 0) Stat[bh * SS + s] = n2;
        }
      }
    }
  }
}

// ---------------- K3: fp32 -> split-bf16 (hi/lo) convert; GV also transposed ----------------
__global__ __launch_bounds__(256) void convert_kernel(
    const float* __restrict__ QKV,   // Q,K,GV contiguous, each [bh][s][dh]
    unsigned short* __restrict__ Qhi, unsigned short* __restrict__ Qlo,
    unsigned short* __restrict__ Khi, unsigned short* __restrict__ Klo,
    unsigned short* __restrict__ GThi, unsigned short* __restrict__ GTlo)
{
  const int st = blockIdx.x, bh = blockIdx.y, mat = blockIdx.z;
  const int tid = threadIdx.x;
  const size_t nQKV = (size_t)BB * NH * SS * DH;
  const float* src = QKV + (size_t)mat * nQKV + ((size_t)bh * SS + st * 64) * DH;
  __shared__ unsigned T[64][69];   // packed (lo<<16)|hi, padded stride

  if (mat < 2) {
    unsigned short* dh_ = ((mat == 0) ? Qhi : Khi) + ((size_t)bh * SS + st * 64) * DH;
    unsigned short* dl_ = ((mat == 0) ? Qlo : Klo) + ((size_t)bh * SS + st * 64) * DH;
    #pragma unroll
    for (int i = 0; i < 4; ++i) {
      const int g = tid + 256 * i;
      const int row = g >> 4, c4 = (g & 15) * 4;
      float4 v = *(const float4*)(src + row * DH + c4);
      float a[4] = {v.x, v.y, v.z, v.w};
      ushort4 hv, lv;
      unsigned short* hp = (unsigned short*)&hv;
      unsigned short* lp = (unsigned short*)&lv;
      #pragma unroll
      for (int j = 0; j < 4; ++j) {
        unsigned short hi = f2bf(a[j]);
        hp[j] = hi;
        lp[j] = f2bf(a[j] - bf2f(hi));
      }
      *(ushort4*)(dh_ + row * DH + c4) = hv;
      *(ushort4*)(dl_ + row * DH + c4) = lv;
    }
  } else {
    #pragma unroll
    for (int i = 0; i < 4; ++i) {
      const int g = tid + 256 * i;
      const int row = g >> 4, c4 = (g & 15) * 4;
      float4 v = *(const float4*)(src + row * DH + c4);
      float a[4] = {v.x, v.y, v.z, v.w};
      #pragma unroll
      for (int j = 0; j < 4; ++j) {
        unsigned short hi = f2bf(a[j]);
        unsigned short lo = f2bf(a[j] - bf2f(hi));
        T[row][c4 + j] = ((unsigned)lo << 16) | (unsigned)hi;
      }
    }
    __syncthreads();
    #pragma unroll
    for (int i = 0; i < 4; ++i) {
      const int g = tid + 256 * i;
      const int kb = g & 15, dhr = g >> 4;
      ushort4 hv, lv;
      unsigned short* hp = (unsigned short*)&hv;
      unsigned short* lp = (unsigned short*)&lv;
      #pragma unroll
      for (int j = 0; j < 4; ++j) {
        unsigned u = T[4 * kb + j][dhr];
        hp[j] = (unsigned short)(u & 0xFFFFu);
        lp[j] = (unsigned short)(u >> 16);
      }
      const size_t ob = ((size_t)bh * DH + dhr) * SS + st * 64 + 4 * kb;
      *(ushort4*)(GThi + ob) = hv;
      *(ushort4*)(GTlo + ob) = lv;
    }
  }
}

// ---------------- K4: MFMA flash-style hyperbolic attention ----------------
__global__ __launch_bounds__(256) void flash_attn_kernel(
    const unsigned short* __restrict__ Qhi, const unsigned short* __restrict__ Qlo,
    const unsigned short* __restrict__ Khi, const unsigned short* __restrict__ Klo,
    const unsigned short* __restrict__ GThi, const unsigned short* __restrict__ GTlo,
    const float* __restrict__ q2a, const float* __restrict__ k2a, const float* __restrict__ gm1a,
    const float* __restrict__ mask, float* __restrict__ out)
{
  constexpr int LDK = 72;
  __shared__ unsigned short Ks_hi[64 * LDK];
  __shared__ unsigned short Ks_lo[64 * LDK];
  __shared__ unsigned short Gs_hi[64 * LDK];
  __shared__ unsigned short Gs_lo[64 * LDK];
  __shared__ float k2s[64], ik2s[64], gm1s[64], ems[64];

  const int qt = blockIdx.x, h = blockIdx.y, b = blockIdx.z;
  const int bh = b * NH + h;
  const int tid = threadIdx.x;
  const int wave = tid >> 6, lane = tid & 63;
  const int tx = lane & 15, quad = lane >> 4;
  const int r0 = qt * 64;

  bf16x8 qa_h[2], qa_l[2];
  {
    const size_t qoff = ((size_t)bh * SS + r0 + 16 * wave + tx) * DH;
    #pragma unroll
    for (int kc = 0; kc < 2; ++kc) {
      qa_h[kc] = *(const bf16x8*)(Qhi + qoff + 32 * kc + 8 * quad);
      qa_l[kc] = *(const bf16x8*)(Qlo + qoff + 32 * kc + 8 * quad);
    }
  }
  float q2r[4], iq2[4];
  #pragma unroll
  for (int r = 0; r < 4; ++r) {
    q2r[r] = q2a[(size_t)bh * SS + r0 + 16 * wave + 4 * quad + r];
    iq2[r] = 2.0f / fmaxf(1.0f - q2r[r], 1e-15f);
  }

  const f32x4 zero4 = {0.f, 0.f, 0.f, 0.f};
  f32x4 oacc[4] = {zero4, zero4, zero4, zero4};
  float dden[4] = {0.f, 0.f, 0.f, 0.f};

  const int c0 = tid, c1 = tid + 256;
  const int sr0 = c0 >> 3, sc0 = (c0 & 7) * 8;
  const int sr1 = c1 >> 3, sc1 = (c1 & 7) * 8;

  for (int kt = 0; kt < 16; ++kt) {
    const int t0 = kt * 64;
    __syncthreads();
    {
      const size_t kb_ = ((size_t)bh * SS + t0) * DH;
      const size_t gb_ = (size_t)bh * DH * SS + t0;
      *(uint4*)&Ks_hi[sr0 * LDK + sc0] = *(const uint4*)(Khi + kb_ + (size_t)sr0 * DH + sc0);
      *(uint4*)&Ks_hi[sr1 * LDK + sc1] = *(const uint4*)(Khi + kb_ + (size_t)sr1 * DH + sc1);
      *(uint4*)&Ks_lo[sr0 * LDK + sc0] = *(const uint4*)(Klo + kb_ + (size_t)sr0 * DH + sc0);
      *(uint4*)&Ks_lo[sr1 * LDK + sc1] = *(const uint4*)(Klo + kb_ + (size_t)sr1 * DH + sc1);
      *(uint4*)&Gs_hi[sr0 * LDK + sc0] = *(const uint4*)(GThi + gb_ + (size_t)sr0 * SS + sc0);
      *(uint4*)&Gs_hi[sr1 * LDK + sc1] = *(const uint4*)(GThi + gb_ + (size_t)sr1 * SS + sc1);
      *(uint4*)&Gs_lo[sr0 * LDK + sc0] = *(const uint4*)(GTlo + gb_ + (size_t)sr0 * SS + sc0);
      *(uint4*)&Gs_lo[sr1 * LDK + sc1] = *(const uint4*)(GTlo + gb_ + (size_t)sr1 * SS + sc1);
      if (tid < 64) {
        float k2v = k2a[(size_t)bh * SS + t0 + tid];
        k2s[tid] = k2v;
        ik2s[tid] = 1.0f / fmaxf(1.0f - k2v, 1e-15f);
        gm1s[tid] = gm1a[(size_t)bh * SS + t0 + tid];
        ems[tid] = __expf(mask[(size_t)b * SS + t0 + tid]);
      }
    }
    __syncthreads();

    f32x4 sacc[4] = {zero4, zero4, zero4, zero4};
    #pragma unroll
    for (int kc = 0; kc < 2; ++kc) {
      const int ko = 32 * kc + 8 * quad;
      #pragma unroll
      for (int nb = 0; nb < 4; ++nb) {
        bf16x8 kh = *(const bf16x8*)&Ks_hi[(16 * nb + tx) * LDK + ko];
        bf16x8 kl = *(const bf16x8*)&Ks_lo[(16 * nb + tx) * LDK + ko];
        sacc[nb] = __builtin_amdgcn_mfma_f32_16x16x32_bf16(qa_h[kc], kh, sacc[nb], 0, 0, 0);
        sacc[nb] = __builtin_amdgcn_mfma_f32_16x16x32_bf16(qa_h[kc], kl, sacc[nb], 0, 0, 0);
        sacc[nb] = __builtin_amdgcn_mfma_f32_16x16x32_bf16(qa_l[kc], kh, sacc[nb], 0, 0, 0);
      }
    }

    float pb[4][4];
    #pragma unroll
    for (int nb = 0; nb < 4; ++nb) {
      const int key = 16 * nb + tx;
      const float k2v = k2s[key], ikv = ik2s[key], emv = ems[key], gmv = gm1s[key];
      #pragma unroll
      for (int r = 0; r < 4; ++r) {
        float sv = sacc[nb][r];
        float num = fmaxf(fmaf(-2.0f, sv, q2r[r] + k2v), 1e-15f);
        float e = num * iq2[r] * ikv;
        float g = fmaf(e, e, e + e);
        float z = 1.0f + e + __builtin_amdgcn_sqrtf(g);
        float w = emv * __builtin_amdgcn_rcpf(z);
        pb[r][nb] = w;
        dden[r] = fmaf(w, gmv, dden[r]);
      }
    }
    __syncthreads();

    #pragma unroll
    for (int r = 0; r < 4; ++r) {
      const int prow = 16 * wave + 4 * quad + r;
      #pragma unroll
      for (int nb = 0; nb < 4; ++nb) {
        float w = pb[r][nb];
        unsigned short hi = f2bf(w);
        unsigned short lo = f2bf(w - bf2f(hi));
        Ks_hi[prow * LDK + 16 * nb + tx] = hi;
        Ks_lo[prow * LDK + 16 * nb + tx] = lo;
      }
    }
    #pragma unroll
    for (int kc = 0; kc < 2; ++kc) {
      const int ko = 32 * kc + 8 * quad;
      bf16x8 ph = *(const bf16x8*)&Ks_hi[(16 * wave + tx) * LDK + ko];
      bf16x8 pl = *(const bf16x8*)&Ks_lo[(16 * wave + tx) * LDK + ko];
      #pragma unroll
      for (int nb = 0; nb < 4; ++nb) {
        bf16x8 gh = *(const bf16x8*)&Gs_hi[(16 * nb + tx) * LDK + ko];
        bf16x8 gl = *(const bf16x8*)&Gs_lo[(16 * nb + tx) * LDK + ko];
        oacc[nb] = __builtin_amdgcn_mfma_f32_16x16x32_bf16(ph, gh, oacc[nb], 0, 0, 0);
        oacc[nb] = __builtin_amdgcn_mfma_f32_16x16x32_bf16(ph, gl, oacc[nb], 0, 0, 0);
        oacc[nb] = __builtin_amdgcn_mfma_f32_16x16x32_bf16(pl, gh, oacc[nb], 0, 0, 0);
      }
    }
  }

  #pragma unroll
  for (int r = 0; r < 4; ++r) {
    float d = fmaxf(xor_sum16(dden[r]), 1e-10f);
    float invd = 1.0f / d;
    float tm[4]; float sq = 0.f;
    #pragma unroll
    for (int nb = 0; nb < 4; ++nb) { tm[nb] = oacc[nb][r] * invd; sq = fmaf(tm[nb], tm[nb], sq); }
    sq = xor_sum16(sq);
    const float f = 1.0f / (1.0f + sqrtf(fmaxf(1.0f - sq, 1e-15f)));
    const float n2 = sq * f * f;
    const float n = fmaxf(sqrtf(n2), 1e-15f);
    const float s2 = (n > MAXN) ? (MAXN / n) : 1.0f;
    const float fs = f * s2;
    const int qrow = r0 + 16 * wave + 4 * quad + r;
    #pragma unroll
    for (int nb = 0; nb < 4; ++nb)
      out[((size_t)(b * SS + qrow)) * DD + h * DH + 16 * nb + tx] = tm[nb] * fs;
  }
}

// ---------------- host ----------------
extern "C" void kernel_launch(void* const* d_in, const int* in_sizes, int n_in,
                              void* d_out, int out_size, void* d_ws, size_t ws_size,
                              hipStream_t stream) {
  const float* hs   = (const float*)d_in[0];
  const float* mask = (const float*)d_in[1];
  const float* qz   = (const float*)d_in[2];
  const float* qr   = (const float*)d_in[3];
  const float* kz   = (const float*)d_in[4];
  const float* kr   = (const float*)d_in[5];
  const float* vz   = (const float*)d_in[6];
  const float* vr   = (const float*)d_in[7];
  float* out = (float*)d_out;

  float* ws = (float*)d_ws;
  const size_t nQKV = (size_t)BB * NH * SS * DH;   // 2,097,152
  const size_t nStat = (size_t)BB * NH * SS;       // 32,768
  float* Q   = ws;                   // Q,K,GV must stay contiguous (convert_kernel)
  float* K   = Q + nQKV;
  float* GV  = K + nQKV;
  float* q2  = GV + nQKV;
  float* k2  = q2 + nStat;
  float* gm1 = k2 + nStat;
  float* zn  = gm1 + nStat;          // 3*1024
  float* c2r = zn + 3 * DD;
  float* s2r = c2r + 3 * DD;
  float* cx2 = s2r + 3 * DD;         // 2048
  unsigned short* bbuf = (unsigned short*)(cx2 + 2048);  // 16B-aligned
  unsigned short* Qhi  = bbuf;
  unsigned short* Qlo  = Qhi  + nQKV;
  unsigned short* Khi  = Qlo  + nQKV;
  unsigned short* Klo  = Khi  + nQKV;
  unsigned short* GThi = Klo  + nQKV;
  unsigned short* GTlo = GThi + nQKV;

  // X/ZT split-bf16 buffers alias bbuf: live only BEFORE convert_kernel writes bbuf.
  const size_t nX = (size_t)BB * SS * DD;          // 2,097,152
  const size_t nZ = (size_t)3 * DD * DD;           // 3,145,728
  unsigned short* Xhi  = bbuf;
  unsigned short* Xlo  = Xhi + nX;
  unsigned short* ZThi = Xlo + nX;
  unsigned short* ZTlo = ZThi + nZ;                // total 10.5M shorts <= 12.6M (bbuf)

  col_stats_kernel<<<dim3(4, 3), 256, 0, stream>>>(qz, kz, vz, qr, kr, vr, zn, c2r, s2r);
  row_cx2_kernel<<<dim3(512), 256, 0, stream>>>(hs, cx2);
  convert_x_kernel<<<dim3(1024), 256, 0, stream>>>(hs, Xhi, Xlo);
  convert_zt_kernel<<<dim3(16, 16, 3), 256, 0, stream>>>(qz, kz, vz, ZThi, ZTlo);
  gemm_mfma_kernel<<<dim3(8, 16, 3), 256, 0, stream>>>(
      Xhi, Xlo, ZThi, ZTlo, zn, c2r, s2r, cx2, Q, K, GV, q2, k2, gm1);
  convert_kernel<<<dim3(16, BB * NH, 3), 256, 0, stream>>>(
      Q, Qhi, Qlo, Khi, Klo, GThi, GTlo);
  flash_attn_kernel<<<dim3(16, NH, BB), 256, 0, stream>>>(
      Qhi, Qlo, Khi, Klo, GThi, GTlo, q2, k2, gm1, mask, out);
}

// Round 5
// 407.579 us; speedup vs baseline: 1.5289x; 1.3400x over previous
//
#include <hip/hip_runtime.h>
#include <math.h>

// Problem constants (C = RC = 1)
#define BB 2
#define SS 1024
#define DD 1024
#define NH 16
#define DH 64
#define MAXN 0.996f   // (1 - PROJ_EPS)/RC

typedef __attribute__((ext_vector_type(8))) short bf16x8;  // MFMA A/B frag (4 VGPRs)
typedef __attribute__((ext_vector_type(4))) float f32x4;   // MFMA C/D frag

__device__ __forceinline__ float xor_sum16(float v){
  v += __shfl_xor(v, 1, 64);
  v += __shfl_xor(v, 2, 64);
  v += __shfl_xor(v, 4, 64);
  v += __shfl_xor(v, 8, 64);
  return v;
}

__device__ __forceinline__ unsigned short f2bf(float x){
  unsigned u = __builtin_bit_cast(unsigned, x);
  unsigned r = u + 0x7FFFu + ((u >> 16) & 1u);   // RNE
  return (unsigned short)(r >> 16);
}
__device__ __forceinline__ float bf2f(unsigned short b){
  unsigned u = ((unsigned)b) << 16;
  return __builtin_bit_cast(float, u);
}

// ---------------- K1a: column norms of z + cosh/sinh(2r) ----------------
__global__ __launch_bounds__(256) void col_stats_kernel(
    const float* __restrict__ zq, const float* __restrict__ zk, const float* __restrict__ zv,
    const float* __restrict__ rq, const float* __restrict__ rk, const float* __restrict__ rv,
    float* __restrict__ zn, float* __restrict__ c2r, float* __restrict__ s2r)
{
  const int m = blockIdx.y;
  const float* z = (m == 0) ? zq : ((m == 1) ? zk : zv);
  const float* r = (m == 0) ? rq : ((m == 1) ? rk : rv);
  const int j = blockIdx.x * 256 + threadIdx.x;   // 0..1023
  float acc = 0.0f;
  for (int i = 0; i < DD; ++i) { float t = z[(size_t)i * DD + j]; acc = fmaf(t, t, acc); }
  float n = fmaxf(sqrtf(acc), 1e-15f);
  zn[m * DD + j] = n;
  float rr = 2.0f * r[j];
  c2r[m * DD + j] = coshf(rr);
  s2r[m * DD + j] = sinhf(rr);
}

// ---------------- K1b: per-row ||x||^2 ----------------
__global__ __launch_bounds__(256) void row_cx2_kernel(const float* __restrict__ x,
                                                      float* __restrict__ cx2)
{
  const int wave = threadIdx.x >> 6;
  const int lane = threadIdx.x & 63;
  const int row = blockIdx.x * 4 + wave;          // 2048 rows, grid 512
  const float* xr = x + (size_t)row * DD;
  float acc = 0.0f;
  for (int i = lane; i < DD; i += 64) { float t = xr[i]; acc = fmaf(t, t, acc); }
  #pragma unroll
  for (int m = 1; m < 64; m <<= 1) acc += __shfl_xor(acc, m, 64);
  if (lane == 0) cx2[row] = acc;
}

// ---------------- K1c: x -> split-bf16 (hi/lo), row-major [m][k] ----------------
__global__ __launch_bounds__(256) void convert_x_kernel(
    const float* __restrict__ x,
    unsigned short* __restrict__ Xhi, unsigned short* __restrict__ Xlo)
{
  const size_t g0 = ((size_t)blockIdx.x * 256 + threadIdx.x) * 8;
  #pragma unroll
  for (int h = 0; h < 2; ++h) {
    float4 v = *(const float4*)(x + g0 + 4 * h);
    float a[4] = {v.x, v.y, v.z, v.w};
    ushort4 hv, lv;
    unsigned short* hp = (unsigned short*)&hv;
    unsigned short* lp = (unsigned short*)&lv;
    #pragma unroll
    for (int j = 0; j < 4; ++j) {
      unsigned short hi = f2bf(a[j]);
      hp[j] = hi;
      lp[j] = f2bf(a[j] - bf2f(hi));
    }
    *(ushort4*)(Xhi + g0 + 4 * h) = hv;
    *(ushort4*)(Xlo + g0 + 4 * h) = lv;
  }
}

// ---------------- K1d: z -> split-bf16 transposed ZT[mat][n][k] ----------------
__global__ __launch_bounds__(256) void convert_zt_kernel(
    const float* __restrict__ zq, const float* __restrict__ zk, const float* __restrict__ zv,
    unsigned short* __restrict__ ZThi, unsigned short* __restrict__ ZTlo)
{
  const int kt = blockIdx.x, nt = blockIdx.y, mat = blockIdx.z;
  const float* z = (mat == 0) ? zq : ((mat == 1) ? zk : zv);
  const int tid = threadIdx.x;
  __shared__ unsigned T[64][69];   // packed (lo<<16)|hi

  #pragma unroll
  for (int i = 0; i < 4; ++i) {
    const int g = tid + 256 * i;
    const int kr = g >> 4, nc = (g & 15) * 4;
    float4 v = *(const float4*)(z + (size_t)(kt * 64 + kr) * DD + nt * 64 + nc);
    float a[4] = {v.x, v.y, v.z, v.w};
    #pragma unroll
    for (int j = 0; j < 4; ++j) {
      unsigned short hi = f2bf(a[j]);
      unsigned short lo = f2bf(a[j] - bf2f(hi));
      T[kr][nc + j] = ((unsigned)lo << 16) | (unsigned)hi;
    }
  }
  __syncthreads();
  #pragma unroll
  for (int i = 0; i < 4; ++i) {
    const int g = tid + 256 * i;
    const int nr = g >> 4, kc = (g & 15) * 4;
    ushort4 hv, lv;
    unsigned short* hp = (unsigned short*)&hv;
    unsigned short* lp = (unsigned short*)&lv;
    #pragma unroll
    for (int j = 0; j < 4; ++j) {
      unsigned u = T[kc + j][nr];
      hp[j] = (unsigned short)(u & 0xFFFFu);
      lp[j] = (unsigned short)(u >> 16);
    }
    const size_t ob = ((size_t)mat * DD + nt * 64 + nr) * DD + kt * 64 + kc;
    *(ushort4*)(ZThi + ob) = hv;
    *(ushort4*)(ZTlo + ob) = lv;
  }
}

// ---------------- K2: split-bf16 MFMA GEMM (x@z) + Poincare-linear epilogue ----------------
// 128x128 tile, K-chunk 32, 4 waves (wave w owns rows [32w,32w+32)).
// Round-3/4 lesson: a f32x4 acc[2][8] ARRAY gets demoted to scratch (promote-alloca
// size heuristic), causing 820 MB of HBM scratch traffic regardless of
// __launch_bounds__. Accumulators are therefore 16 individually-NAMED f32x4
// SSA values, expanded via macros.
__global__ __launch_bounds__(256, 2) void gemm_mfma_kernel(
    const unsigned short* __restrict__ Xhi, const unsigned short* __restrict__ Xlo,
    const unsigned short* __restrict__ ZThi, const unsigned short* __restrict__ ZTlo,
    const float* __restrict__ zn, const float* __restrict__ c2r, const float* __restrict__ s2r,
    const float* __restrict__ cx2,
    float* __restrict__ Q, float* __restrict__ K, float* __restrict__ GV,
    float* __restrict__ q2, float* __restrict__ k2, float* __restrict__ gm1)
{
  constexpr int LDK = 40;                    // halfword stride (80 B) -> ~2-way on frag reads, free
  __shared__ unsigned short Xs_hi[128 * LDK], Xs_lo[128 * LDK];
  __shared__ unsigned short Zs_hi[128 * LDK], Zs_lo[128 * LDK];

  const int mat = blockIdx.z;
  float* OutM = (mat == 0) ? Q  : ((mat == 1) ? K  : GV);
  float* Stat = (mat == 0) ? q2 : ((mat == 1) ? k2 : gm1);

  const int n0 = blockIdx.x * 128;
  const int m0 = blockIdx.y * 128;
  const int tid = threadIdx.x;
  const int wave = tid >> 6, lane = tid & 63;
  const int tx = lane & 15, quad = lane >> 4;

  // staging mapping: 512 slots of (row, 8-halfword chunk)
  const int r_a = tid >> 2,         c_a = (tid & 3) * 8;
  const int r_b = (tid + 256) >> 2, c_b = ((tid + 256) & 3) * 8;

  const unsigned short* Xh = Xhi + (size_t)m0 * DD;
  const unsigned short* Xl = Xlo + (size_t)m0 * DD;
  const unsigned short* Zh = ZThi + ((size_t)mat * DD + n0) * DD;
  const unsigned short* Zl = ZTlo + ((size_t)mat * DD + n0) * DD;

  const f32x4 z4 = {0.f, 0.f, 0.f, 0.f};
  f32x4 c00 = z4, c01 = z4, c02 = z4, c03 = z4, c04 = z4, c05 = z4, c06 = z4, c07 = z4;
  f32x4 c10 = z4, c11 = z4, c12 = z4, c13 = z4, c14 = z4, c15 = z4, c16 = z4, c17 = z4;

  for (int kt = 0; kt < 32; ++kt) {
    const int k0 = kt * 32;
    // global loads issued before the barrier (no LDS dependence)
    uint4 xa_h = *(const uint4*)(Xh + (size_t)r_a * DD + k0 + c_a);
    uint4 xb_h = *(const uint4*)(Xh + (size_t)r_b * DD + k0 + c_b);
    uint4 xa_l = *(const uint4*)(Xl + (size_t)r_a * DD + k0 + c_a);
    uint4 xb_l = *(const uint4*)(Xl + (size_t)r_b * DD + k0 + c_b);
    uint4 za_h = *(const uint4*)(Zh + (size_t)r_a * DD + k0 + c_a);
    uint4 zb_h = *(const uint4*)(Zh + (size_t)r_b * DD + k0 + c_b);
    uint4 za_l = *(const uint4*)(Zl + (size_t)r_a * DD + k0 + c_a);
    uint4 zb_l = *(const uint4*)(Zl + (size_t)r_b * DD + k0 + c_b);
    __syncthreads();
    *(uint4*)&Xs_hi[r_a * LDK + c_a] = xa_h;
    *(uint4*)&Xs_hi[r_b * LDK + c_b] = xb_h;
    *(uint4*)&Xs_lo[r_a * LDK + c_a] = xa_l;
    *(uint4*)&Xs_lo[r_b * LDK + c_b] = xb_l;
    *(uint4*)&Zs_hi[r_a * LDK + c_a] = za_h;
    *(uint4*)&Zs_hi[r_b * LDK + c_b] = zb_h;
    *(uint4*)&Zs_lo[r_a * LDK + c_a] = za_l;
    *(uint4*)&Zs_lo[r_b * LDK + c_b] = zb_l;
    __syncthreads();

    const int arow = 32 * wave + tx;
    bf16x8 a_h0 = *(const bf16x8*)&Xs_hi[arow * LDK + 8 * quad];
    bf16x8 a_l0 = *(const bf16x8*)&Xs_lo[arow * LDK + 8 * quad];
    bf16x8 a_h1 = *(const bf16x8*)&Xs_hi[(arow + 16) * LDK + 8 * quad];
    bf16x8 a_l1 = *(const bf16x8*)&Xs_lo[(arow + 16) * LDK + 8 * quad];

#define DO_NB(NB, C0, C1) { \
      bf16x8 b_h = *(const bf16x8*)&Zs_hi[(16 * NB + tx) * LDK + 8 * quad]; \
      bf16x8 b_l = *(const bf16x8*)&Zs_lo[(16 * NB + tx) * LDK + 8 * quad]; \
      C0 = __builtin_amdgcn_mfma_f32_16x16x32_bf16(a_h0, b_h, C0, 0, 0, 0); \
      C0 = __builtin_amdgcn_mfma_f32_16x16x32_bf16(a_h0, b_l, C0, 0, 0, 0); \
      C0 = __builtin_amdgcn_mfma_f32_16x16x32_bf16(a_l0, b_h, C0, 0, 0, 0); \
      C1 = __builtin_amdgcn_mfma_f32_16x16x32_bf16(a_h1, b_h, C1, 0, 0, 0); \
      C1 = __builtin_amdgcn_mfma_f32_16x16x32_bf16(a_h1, b_l, C1, 0, 0, 0); \
      C1 = __builtin_amdgcn_mfma_f32_16x16x32_bf16(a_l1, b_h, C1, 0, 0, 0); }
    DO_NB(0, c00, c10)
    DO_NB(1, c01, c11)
    DO_NB(2, c02, c12)
    DO_NB(3, c03, c13)
    DO_NB(4, c04, c14)
    DO_NB(5, c05, c15)
    DO_NB(6, c06, c16)
    DO_NB(7, c07, c17)
#undef DO_NB
  }

  // Epilogue. C/D layout: col = tx, row = 4*quad + reg.
  auto epi_mb = [&](int mb, f32x4 d0, f32x4 d1, f32x4 d2, f32x4 d3,
                    f32x4 d4, f32x4 d5, f32x4 d6, f32x4 d7) {
    #pragma unroll
    for (int r = 0; r < 4; ++r) {
      const int row = m0 + 32 * wave + 16 * mb + 4 * quad + r;
      const float c2 = cx2[row];
      const float inv = 1.0f / fmaxf(1.0f - c2, 1e-15f);
      const float onec = 1.0f + c2;
      float yv[8];
      #pragma unroll
      for (int nb = 0; nb < 8; ++nb) {
        const float accv = (nb == 0) ? d0[r] : (nb == 1) ? d1[r] : (nb == 2) ? d2[r] :
                           (nb == 3) ? d3[r] : (nb == 4) ? d4[r] : (nb == 5) ? d5[r] :
                           (nb == 6) ? d6[r] : d7[r];
        const int col = mat * DD + n0 + 16 * nb + tx;
        const float znv = zn[col];
        const float u = (2.0f * (accv / znv) * c2r[col] - onec * s2r[col]) * inv;
        const float w = 2.0f * znv * asinhf(u);
        yv[nb] = sinhf(w);
      }
      const int b = row >> 10, s = row & 1023;
      #pragma unroll
      for (int hg = 0; hg < 2; ++hg) {       // two heads per 128-col tile
        float n2 = 0.f;
        #pragma unroll
        for (int j = 0; j < 4; ++j) n2 = fmaf(yv[4*hg+j], yv[4*hg+j], n2);
        n2 = xor_sum16(n2);
        float n = fmaxf(sqrtf(n2), 1e-15f);
        float s1 = (n > MAXN) ? (MAXN / n) : 1.0f;      // project #1
        n2 = n2 * s1 * s1;
        float f = 1.0f / (1.0f + sqrtf(1.0f + n2));     // exp-map scaling
        float fs = s1 * f;
        n2 = n2 * f * f;
        float nb2 = fmaxf(sqrtf(n2), 1e-15f);
        float s2f = (nb2 > MAXN) ? (MAXN / nb2) : 1.0f; // project #2
        fs *= s2f;
        n2 = n2 * s2f * s2f;

        const int head = blockIdx.x * 2 + hg;
        const size_t bh = (size_t)(b * NH + head);
        const size_t outbase = (bh * SS + s) * DH;
        if (mat == 2) {
          const float gamma = 2.0f / fmaxf(1.0f - n2, 1e-15f);
          #pragma unroll
          for (int j = 0; j < 4; ++j)
            OutM[outbase + 16 * j + tx] = yv[4*hg+j] * fs * gamma;
          if (tx == 0) Stat[bh * SS + s] = gamma - 1.0f;
        } else {
          #pragma unroll
          for (int j = 0; j < 4; ++j)
            OutM[outbase + 16 * j + tx] = yv[4*hg+j] * fs;
          if (tx == 0) Stat[bh * SS + s] = n2;
        }
      }
    }
  };
  epi_mb(0, c00, c01, c02, c03, c04, c05, c06, c07);
  epi_mb(1, c10, c11, c12, c13, c14, c15, c16, c17);
}

// ---------------- K3: fp32 -> split-bf16 (hi/lo) convert; GV also transposed ----------------
__global__ __launch_bounds__(256) void convert_kernel(
    const float* __restrict__ QKV,   // Q,K,GV contiguous, each [bh][s][dh]
    unsigned short* __restrict__ Qhi, unsigned short* __restrict__ Qlo,
    unsigned short* __restrict__ Khi, unsigned short* __restrict__ Klo,
    unsigned short* __restrict__ GThi, unsigned short* __restrict__ GTlo)
{
  const int st = blockIdx.x, bh = blockIdx.y, mat = blockIdx.z;
  const int tid = threadIdx.x;
  const size_t nQKV = (size_t)BB * NH * SS * DH;
  const float* src = QKV + (size_t)mat * nQKV + ((size_t)bh * SS + st * 64) * DH;
  __shared__ unsigned T[64][69];   // packed (lo<<16)|hi, padded stride

  if (mat < 2) {
    unsigned short* dh_ = ((mat == 0) ? Qhi : Khi) + ((size_t)bh * SS + st * 64) * DH;
    unsigned short* dl_ = ((mat == 0) ? Qlo : Klo) + ((size_t)bh * SS + st * 64) * DH;
    #pragma unroll
    for (int i = 0; i < 4; ++i) {
      const int g = tid + 256 * i;
      const int row = g >> 4, c4 = (g & 15) * 4;
      float4 v = *(const float4*)(src + row * DH + c4);
      float a[4] = {v.x, v.y, v.z, v.w};
      ushort4 hv, lv;
      unsigned short* hp = (unsigned short*)&hv;
      unsigned short* lp = (unsigned short*)&lv;
      #pragma unroll
      for (int j = 0; j < 4; ++j) {
        unsigned short hi = f2bf(a[j]);
        hp[j] = hi;
        lp[j] = f2bf(a[j] - bf2f(hi));
      }
      *(ushort4*)(dh_ + row * DH + c4) = hv;
      *(ushort4*)(dl_ + row * DH + c4) = lv;
    }
  } else {
    #pragma unroll
    for (int i = 0; i < 4; ++i) {
      const int g = tid + 256 * i;
      const int row = g >> 4, c4 = (g & 15) * 4;
      float4 v = *(const float4*)(src + row * DH + c4);
      float a[4] = {v.x, v.y, v.z, v.w};
      #pragma unroll
      for (int j = 0; j < 4; ++j) {
        unsigned short hi = f2bf(a[j]);
        unsigned short lo = f2bf(a[j] - bf2f(hi));
        T[row][c4 + j] = ((unsigned)lo << 16) | (unsigned)hi;
      }
    }
    __syncthreads();
    #pragma unroll
    for (int i = 0; i < 4; ++i) {
      const int g = tid + 256 * i;
      const int kb = g & 15, dhr = g >> 4;
      ushort4 hv, lv;
      unsigned short* hp = (unsigned short*)&hv;
      unsigned short* lp = (unsigned short*)&lv;
      #pragma unroll
      for (int j = 0; j < 4; ++j) {
        unsigned u = T[4 * kb + j][dhr];
        hp[j] = (unsigned short)(u & 0xFFFFu);
        lp[j] = (unsigned short)(u >> 16);
      }
      const size_t ob = ((size_t)bh * DH + dhr) * SS + st * 64 + 4 * kb;
      *(ushort4*)(GThi + ob) = hv;
      *(ushort4*)(GTlo + ob) = lv;
    }
  }
}

// ---------------- K4: MFMA flash-style hyperbolic attention ----------------
__global__ __launch_bounds__(256) void flash_attn_kernel(
    const unsigned short* __restrict__ Qhi, const unsigned short* __restrict__ Qlo,
    const unsigned short* __restrict__ Khi, const unsigned short* __restrict__ Klo,
    const unsigned short* __restrict__ GThi, const unsigned short* __restrict__ GTlo,
    const float* __restrict__ q2a, const float* __restrict__ k2a, const float* __restrict__ gm1a,
    const float* __restrict__ mask, float* __restrict__ out)
{
  constexpr int LDK = 72;
  __shared__ unsigned short Ks_hi[64 * LDK];
  __shared__ unsigned short Ks_lo[64 * LDK];
  __shared__ unsigned short Gs_hi[64 * LDK];
  __shared__ unsigned short Gs_lo[64 * LDK];
  __shared__ float k2s[64], ik2s[64], gm1s[64], ems[64];

  const int qt = blockIdx.x, h = blockIdx.y, b = blockIdx.z;
  const int bh = b * NH + h;
  const int tid = threadIdx.x;
  const int wave = tid >> 6, lane = tid & 63;
  const int tx = lane & 15, quad = lane >> 4;
  const int r0 = qt * 64;

  bf16x8 qa_h[2], qa_l[2];
  {
    const size_t qoff = ((size_t)bh * SS + r0 + 16 * wave + tx) * DH;
    #pragma unroll
    for (int kc = 0; kc < 2; ++kc) {
      qa_h[kc] = *(const bf16x8*)(Qhi + qoff + 32 * kc + 8 * quad);
      qa_l[kc] = *(const bf16x8*)(Qlo + qoff + 32 * kc + 8 * quad);
    }
  }
  float q2r[4], iq2[4];
  #pragma unroll
  for (int r = 0; r < 4; ++r) {
    q2r[r] = q2a[(size_t)bh * SS + r0 + 16 * wave + 4 * quad + r];
    iq2[r] = 2.0f / fmaxf(1.0f - q2r[r], 1e-15f);
  }

  const f32x4 zero4 = {0.f, 0.f, 0.f, 0.f};
  f32x4 oacc[4] = {zero4, zero4, zero4, zero4};
  float dden[4] = {0.f, 0.f, 0.f, 0.f};

  const int c0 = tid, c1 = tid + 256;
  const int sr0 = c0 >> 3, sc0 = (c0 & 7) * 8;
  const int sr1 = c1 >> 3, sc1 = (c1 & 7) * 8;

  for (int kt = 0; kt < 16; ++kt) {
    const int t0 = kt * 64;
    __syncthreads();
    {
      const size_t kb_ = ((size_t)bh * SS + t0) * DH;
      const size_t gb_ = (size_t)bh * DH * SS + t0;
      *(uint4*)&Ks_hi[sr0 * LDK + sc0] = *(const uint4*)(Khi + kb_ + (size_t)sr0 * DH + sc0);
      *(uint4*)&Ks_hi[sr1 * LDK + sc1] = *(const uint4*)(Khi + kb_ + (size_t)sr1 * DH + sc1);
      *(uint4*)&Ks_lo[sr0 * LDK + sc0] = *(const uint4*)(Klo + kb_ + (size_t)sr0 * DH + sc0);
      *(uint4*)&Ks_lo[sr1 * LDK + sc1] = *(const uint4*)(Klo + kb_ + (size_t)sr1 * DH + sc1);
      *(uint4*)&Gs_hi[sr0 * LDK + sc0] = *(const uint4*)(GThi + gb_ + (size_t)sr0 * SS + sc0);
      *(uint4*)&Gs_hi[sr1 * LDK + sc1] = *(const uint4*)(GThi + gb_ + (size_t)sr1 * SS + sc1);
      *(uint4*)&Gs_lo[sr0 * LDK + sc0] = *(const uint4*)(GTlo + gb_ + (size_t)sr0 * SS + sc0);
      *(uint4*)&Gs_lo[sr1 * LDK + sc1] = *(const uint4*)(GTlo + gb_ + (size_t)sr1 * SS + sc1);
      if (tid < 64) {
        float k2v = k2a[(size_t)bh * SS + t0 + tid];
        k2s[tid] = k2v;
        ik2s[tid] = 1.0f / fmaxf(1.0f - k2v, 1e-15f);
        gm1s[tid] = gm1a[(size_t)bh * SS + t0 + tid];
        ems[tid] = __expf(mask[(size_t)b * SS + t0 + tid]);
      }
    }
    __syncthreads();

    f32x4 sacc[4] = {zero4, zero4, zero4, zero4};
    #pragma unroll
    for (int kc = 0; kc < 2; ++kc) {
      const int ko = 32 * kc + 8 * quad;
      #pragma unroll
      for (int nb = 0; nb < 4; ++nb) {
        bf16x8 kh = *(const bf16x8*)&Ks_hi[(16 * nb + tx) * LDK + ko];
        bf16x8 kl = *(const bf16x8*)&Ks_lo[(16 * nb + tx) * LDK + ko];
        sacc[nb] = __builtin_amdgcn_mfma_f32_16x16x32_bf16(qa_h[kc], kh, sacc[nb], 0, 0, 0);
        sacc[nb] = __builtin_amdgcn_mfma_f32_16x16x32_bf16(qa_h[kc], kl, sacc[nb], 0, 0, 0);
        sacc[nb] = __builtin_amdgcn_mfma_f32_16x16x32_bf16(qa_l[kc], kh, sacc[nb], 0, 0, 0);
      }
    }

    float pb[4][4];
    #pragma unroll
    for (int nb = 0; nb < 4; ++nb) {
      const int key = 16 * nb + tx;
      const float k2v = k2s[key], ikv = ik2s[key], emv = ems[key], gmv = gm1s[key];
      #pragma unroll
      for (int r = 0; r < 4; ++r) {
        float sv = sacc[nb][r];
        float num = fmaxf(fmaf(-2.0f, sv, q2r[r] + k2v), 1e-15f);
        float e = num * iq2[r] * ikv;
        float g = fmaf(e, e, e + e);
        float z = 1.0f + e + __builtin_amdgcn_sqrtf(g);
        float w = emv * __builtin_amdgcn_rcpf(z);
        pb[r][nb] = w;
        dden[r] = fmaf(w, gmv, dden[r]);
      }
    }
    __syncthreads();

    #pragma unroll
    for (int r = 0; r < 4; ++r) {
      const int prow = 16 * wave + 4 * quad + r;
      #pragma unroll
      for (int nb = 0; nb < 4; ++nb) {
        float w = pb[r][nb];
        unsigned short hi = f2bf(w);
        unsigned short lo = f2bf(w - bf2f(hi));
        Ks_hi[prow * LDK + 16 * nb + tx] = hi;
        Ks_lo[prow * LDK + 16 * nb + tx] = lo;
      }
    }
    #pragma unroll
    for (int kc = 0; kc < 2; ++kc) {
      const int ko = 32 * kc + 8 * quad;
      bf16x8 ph = *(const bf16x8*)&Ks_hi[(16 * wave + tx) * LDK + ko];
      bf16x8 pl = *(const bf16x8*)&Ks_lo[(16 * wave + tx) * LDK + ko];
      #pragma unroll
      for (int nb = 0; nb < 4; ++nb) {
        bf16x8 gh = *(const bf16x8*)&Gs_hi[(16 * nb + tx) * LDK + ko];
        bf16x8 gl = *(const bf16x8*)&Gs_lo[(16 * nb + tx) * LDK + ko];
        oacc[nb] = __builtin_amdgcn_mfma_f32_16x16x32_bf16(ph, gh, oacc[nb], 0, 0, 0);
        oacc[nb] = __builtin_amdgcn_mfma_f32_16x16x32_bf16(ph, gl, oacc[nb], 0, 0, 0);
        oacc[nb] = __builtin_amdgcn_mfma_f32_16x16x32_bf16(pl, gh, oacc[nb], 0, 0, 0);
      }
    }
  }

  #pragma unroll
  for (int r = 0; r < 4; ++r) {
    float d = fmaxf(xor_sum16(dden[r]), 1e-10f);
    float invd = 1.0f / d;
    float tm[4]; float sq = 0.f;
    #pragma unroll
    for (int nb = 0; nb < 4; ++nb) { tm[nb] = oacc[nb][r] * invd; sq = fmaf(tm[nb], tm[nb], sq); }
    sq = xor_sum16(sq);
    const float f = 1.0f / (1.0f + sqrtf(fmaxf(1.0f - sq, 1e-15f)));
    const float n2 = sq * f * f;
    const float n = fmaxf(sqrtf(n2), 1e-15f);
    const float s2 = (n > MAXN) ? (MAXN / n) : 1.0f;
    const float fs = f * s2;
    const int qrow = r0 + 16 * wave + 4 * quad + r;
    #pragma unroll
    for (int nb = 0; nb < 4; ++nb)
      out[((size_t)(b * SS + qrow)) * DD + h * DH + 16 * nb + tx] = tm[nb] * fs;
  }
}

// ---------------- host ----------------
extern "C" void kernel_launch(void* const* d_in, const int* in_sizes, int n_in,
                              void* d_out, int out_size, void* d_ws, size_t ws_size,
                              hipStream_t stream) {
  const float* hs   = (const float*)d_in[0];
  const float* mask = (const float*)d_in[1];
  const float* qz   = (const float*)d_in[2];
  const float* qr   = (const float*)d_in[3];
  const float* kz   = (const float*)d_in[4];
  const float* kr   = (const float*)d_in[5];
  const float* vz   = (const float*)d_in[6];
  const float* vr   = (const float*)d_in[7];
  float* out = (float*)d_out;

  float* ws = (float*)d_ws;
  const size_t nQKV = (size_t)BB * NH * SS * DH;   // 2,097,152
  const size_t nStat = (size_t)BB * NH * SS;       // 32,768
  float* Q   = ws;                   // Q,K,GV must stay contiguous (convert_kernel)
  float* K   = Q + nQKV;
  float* GV  = K + nQKV;
  float* q2  = GV + nQKV;
  float* k2  = q2 + nStat;
  float* gm1 = k2 + nStat;
  float* zn  = gm1 + nStat;          // 3*1024
  float* c2r = zn + 3 * DD;
  float* s2r = c2r + 3 * DD;
  float* cx2 = s2r + 3 * DD;         // 2048
  unsigned short* bbuf = (unsigned short*)(cx2 + 2048);  // 16B-aligned
  unsigned short* Qhi  = bbuf;
  unsigned short* Qlo  = Qhi  + nQKV;
  unsigned short* Khi  = Qlo  + nQKV;
  unsigned short* Klo  = Khi  + nQKV;
  unsigned short* GThi = Klo  + nQKV;
  unsigned short* GTlo = GThi + nQKV;

  // X/ZT split-bf16 buffers alias bbuf: live only BEFORE convert_kernel writes bbuf.
  const size_t nX = (size_t)BB * SS * DD;          // 2,097,152
  const size_t nZ = (size_t)3 * DD * DD;           // 3,145,728
  unsigned short* Xhi  = bbuf;
  unsigned short* Xlo  = Xhi + nX;
  unsigned short* ZThi = Xlo + nX;
  unsigned short* ZTlo = ZThi + nZ;                // total 10.5M shorts <= 12.6M (bbuf)

  col_stats_kernel<<<dim3(4, 3), 256, 0, stream>>>(qz, kz, vz, qr, kr, vr, zn, c2r, s2r);
  row_cx2_kernel<<<dim3(512), 256, 0, stream>>>(hs, cx2);
  convert_x_kernel<<<dim3(1024), 256, 0, stream>>>(hs, Xhi, Xlo);
  convert_zt_kernel<<<dim3(16, 16, 3), 256, 0, stream>>>(qz, kz, vz, ZThi, ZTlo);
  gemm_mfma_kernel<<<dim3(8, 16, 3), 256, 0, stream>>>(
      Xhi, Xlo, ZThi, ZTlo, zn, c2r, s2r, cx2, Q, K, GV, q2, k2, gm1);
  convert_kernel<<<dim3(16, BB * NH, 3), 256, 0, stream>>>(
      Q, Qhi, Qlo, Khi, Klo, GThi, GTlo);
  flash_attn_kernel<<<dim3(16, NH, BB), 256, 0, stream>>>(
      Qhi, Qlo, Khi, Klo, GThi, GTlo, q2, k2, gm1, mask, out);
}

// Round 6
// 277.705 us; speedup vs baseline: 2.2439x; 1.4677x over previous
//
#include <hip/hip_runtime.h>
#include <math.h>

// Problem constants (C = RC = 1)
#define BB 2
#define SS 1024
#define DD 1024
#define NH 16
#define DH 64
#define MAXN 0.996f   // (1 - PROJ_EPS)/RC

typedef __attribute__((ext_vector_type(8))) short bf16x8;  // MFMA A/B frag (4 VGPRs)
typedef __attribute__((ext_vector_type(4))) float f32x4;   // MFMA C/D frag

__device__ __forceinline__ float xor_sum16(float v){
  v += __shfl_xor(v, 1, 64);
  v += __shfl_xor(v, 2, 64);
  v += __shfl_xor(v, 4, 64);
  v += __shfl_xor(v, 8, 64);
  return v;
}

__device__ __forceinline__ unsigned short f2bf(float x){
  unsigned u = __builtin_bit_cast(unsigned, x);
  unsigned r = u + 0x7FFFu + ((u >> 16) & 1u);   // RNE
  return (unsigned short)(r >> 16);
}
__device__ __forceinline__ float bf2f(unsigned short b){
  unsigned u = ((unsigned)b) << 16;
  return __builtin_bit_cast(float, u);
}

// ---------------- K1a: column norms of z + cosh/sinh(2r) ----------------
// grid (16, 3): 64 cols/block, row-sum split 4-way + LDS reduce (was 12 blocks total).
__global__ __launch_bounds__(256) void col_stats_kernel(
    const float* __restrict__ zq, const float* __restrict__ zk, const float* __restrict__ zv,
    const float* __restrict__ rq, const float* __restrict__ rk, const float* __restrict__ rv,
    float* __restrict__ zn, float* __restrict__ c2r, float* __restrict__ s2r)
{
  const int m = blockIdx.y;
  const float* z = (m == 0) ? zq : ((m == 1) ? zk : zv);
  const float* r = (m == 0) ? rq : ((m == 1) ? rk : rv);
  const int col = blockIdx.x * 64 + (threadIdx.x & 63);
  const int slice = threadIdx.x >> 6;             // 0..3
  float acc = 0.0f;
  for (int i = slice * 256; i < slice * 256 + 256; ++i) {
    float t = z[(size_t)i * DD + col]; acc = fmaf(t, t, acc);
  }
  __shared__ float red[4][64];
  red[slice][threadIdx.x & 63] = acc;
  __syncthreads();
  if (slice == 0) {
    const int c = threadIdx.x & 63;
    float a = red[0][c] + red[1][c] + red[2][c] + red[3][c];
    float n = fmaxf(sqrtf(a), 1e-15f);
    zn[m * DD + col] = n;
    float rr = 2.0f * r[col];
    c2r[m * DD + col] = coshf(rr);
    s2r[m * DD + col] = sinhf(rr);
  }
}

// ---------------- K1b: per-row ||x||^2 ----------------
__global__ __launch_bounds__(256) void row_cx2_kernel(const float* __restrict__ x,
                                                      float* __restrict__ cx2)
{
  const int wave = threadIdx.x >> 6;
  const int lane = threadIdx.x & 63;
  const int row = blockIdx.x * 4 + wave;          // 2048 rows, grid 512
  const float* xr = x + (size_t)row * DD;
  float acc = 0.0f;
  for (int i = lane; i < DD; i += 64) { float t = xr[i]; acc = fmaf(t, t, acc); }
  #pragma unroll
  for (int m = 1; m < 64; m <<= 1) acc += __shfl_xor(acc, m, 64);
  if (lane == 0) cx2[row] = acc;
}

// ---------------- K1c: x -> split-bf16 (hi/lo), row-major [m][k] ----------------
__global__ __launch_bounds__(256) void convert_x_kernel(
    const float* __restrict__ x,
    unsigned short* __restrict__ Xhi, unsigned short* __restrict__ Xlo)
{
  const size_t g0 = ((size_t)blockIdx.x * 256 + threadIdx.x) * 8;
  #pragma unroll
  for (int h = 0; h < 2; ++h) {
    float4 v = *(const float4*)(x + g0 + 4 * h);
    float a[4] = {v.x, v.y, v.z, v.w};
    ushort4 hv, lv;
    unsigned short* hp = (unsigned short*)&hv;
    unsigned short* lp = (unsigned short*)&lv;
    #pragma unroll
    for (int j = 0; j < 4; ++j) {
      unsigned short hi = f2bf(a[j]);
      hp[j] = hi;
      lp[j] = f2bf(a[j] - bf2f(hi));
    }
    *(ushort4*)(Xhi + g0 + 4 * h) = hv;
    *(ushort4*)(Xlo + g0 + 4 * h) = lv;
  }
}

// ---------------- K1d: z -> split-bf16 transposed ZT[mat][n][k] ----------------
__global__ __launch_bounds__(256) void convert_zt_kernel(
    const float* __restrict__ zq, const float* __restrict__ zk, const float* __restrict__ zv,
    unsigned short* __restrict__ ZThi, unsigned short* __restrict__ ZTlo)
{
  const int kt = blockIdx.x, nt = blockIdx.y, mat = blockIdx.z;
  const float* z = (mat == 0) ? zq : ((mat == 1) ? zk : zv);
  const int tid = threadIdx.x;
  __shared__ unsigned T[64][69];   // packed (lo<<16)|hi

  #pragma unroll
  for (int i = 0; i < 4; ++i) {
    const int g = tid + 256 * i;
    const int kr = g >> 4, nc = (g & 15) * 4;
    float4 v = *(const float4*)(z + (size_t)(kt * 64 + kr) * DD + nt * 64 + nc);
    float a[4] = {v.x, v.y, v.z, v.w};
    #pragma unroll
    for (int j = 0; j < 4; ++j) {
      unsigned short hi = f2bf(a[j]);
      unsigned short lo = f2bf(a[j] - bf2f(hi));
      T[kr][nc + j] = ((unsigned)lo << 16) | (unsigned)hi;
    }
  }
  __syncthreads();
  #pragma unroll
  for (int i = 0; i < 4; ++i) {
    const int g = tid + 256 * i;
    const int nr = g >> 4, kc = (g & 15) * 4;
    ushort4 hv, lv;
    unsigned short* hp = (unsigned short*)&hv;
    unsigned short* lp = (unsigned short*)&lv;
    #pragma unroll
    for (int j = 0; j < 4; ++j) {
      unsigned u = T[kc + j][nr];
      hp[j] = (unsigned short)(u & 0xFFFFu);
      lp[j] = (unsigned short)(u >> 16);
    }
    const size_t ob = ((size_t)mat * DD + nt * 64 + nr) * DD + kt * 64 + kc;
    *(ushort4*)(ZThi + ob) = hv;
    *(ushort4*)(ZTlo + ob) = lv;
  }
}

// ---------------- K2: split-bf16 MFMA GEMM (x@z) + Poincare-linear epilogue ----------------
// v3: 128x128 tile, BK=32, 512 threads / 8 waves (wave w owns rows [16w,16w+16)).
// Round-5 lesson: with loads issued right before the barrier, the compiler's
// s_waitcnt vmcnt(0)-before-s_barrier exposes full L2 latency every K-iter at
// 6 waves/CU -> MfmaUtil 7%. Fix: REGISTER PREFETCH - tile kt+1's global loads
// issue right after the LDS-ready barrier, BEFORE the MFMA phase, so the drain
// at the next barrier lands after ~1000 cyc of compute. 8 waves halve per-wave
// acc (8 named f32x4, no arrays -> no scratch demotion) -> ~2 blocks/CU.
__global__ __launch_bounds__(512, 2) void gemm_mfma_kernel(
    const unsigned short* __restrict__ Xhi, const unsigned short* __restrict__ Xlo,
    const unsigned short* __restrict__ ZThi, const unsigned short* __restrict__ ZTlo,
    const float* __restrict__ zn, const float* __restrict__ c2r, const float* __restrict__ s2r,
    const float* __restrict__ cx2,
    float* __restrict__ Q, float* __restrict__ K, float* __restrict__ GV,
    float* __restrict__ q2, float* __restrict__ k2, float* __restrict__ gm1)
{
  constexpr int LDK = 40;                    // halfword stride (80 B)
  __shared__ unsigned short Xs_hi[128 * LDK], Xs_lo[128 * LDK];
  __shared__ unsigned short Zs_hi[128 * LDK], Zs_lo[128 * LDK];

  const int mat = blockIdx.z;
  float* OutM = (mat == 0) ? Q  : ((mat == 1) ? K  : GV);
  float* Stat = (mat == 0) ? q2 : ((mat == 1) ? k2 : gm1);

  const int n0 = blockIdx.x * 128;
  const int m0 = blockIdx.y * 128;
  const int tid = threadIdx.x;
  const int wave = tid >> 6, lane = tid & 63;
  const int tx = lane & 15, quad = lane >> 4;

  // staging: one uint4 slot per thread per buffer (512 slots = 128 rows x 4 chunks)
  const int r_s = tid >> 2, c_s = (tid & 3) * 8;

  const unsigned short* Xh = Xhi + (size_t)m0 * DD + (size_t)r_s * DD + c_s;
  const unsigned short* Xl = Xlo + (size_t)m0 * DD + (size_t)r_s * DD + c_s;
  const unsigned short* Zh = ZThi + ((size_t)mat * DD + n0 + r_s) * DD + c_s;
  const unsigned short* Zl = ZTlo + ((size_t)mat * DD + n0 + r_s) * DD + c_s;

  const f32x4 z4 = {0.f, 0.f, 0.f, 0.f};
  f32x4 d0 = z4, d1 = z4, d2 = z4, d3 = z4, d4 = z4, d5 = z4, d6 = z4, d7 = z4;

  // prologue prefetch (tile 0)
  uint4 px_h = *(const uint4*)(Xh);
  uint4 px_l = *(const uint4*)(Xl);
  uint4 pz_h = *(const uint4*)(Zh);
  uint4 pz_l = *(const uint4*)(Zl);

  for (int kt = 0; kt < 32; ++kt) {
    __syncthreads();                         // consumers of previous tile done
    *(uint4*)&Xs_hi[r_s * LDK + c_s] = px_h;
    *(uint4*)&Xs_lo[r_s * LDK + c_s] = px_l;
    *(uint4*)&Zs_hi[r_s * LDK + c_s] = pz_h;
    *(uint4*)&Zs_lo[r_s * LDK + c_s] = pz_l;
    __syncthreads();                         // tile ready
    if (kt < 31) {                           // prefetch kt+1 BEFORE the MFMA phase
      const int k1 = (kt + 1) * 32;
      px_h = *(const uint4*)(Xh + k1);
      px_l = *(const uint4*)(Xl + k1);
      pz_h = *(const uint4*)(Zh + k1);
      pz_l = *(const uint4*)(Zl + k1);
    }

    const int arow = 16 * wave + tx;
    bf16x8 a_h = *(const bf16x8*)&Xs_hi[arow * LDK + 8 * quad];
    bf16x8 a_l = *(const bf16x8*)&Xs_lo[arow * LDK + 8 * quad];

#define DO_NB(NB, C) { \
      bf16x8 b_h = *(const bf16x8*)&Zs_hi[(16 * NB + tx) * LDK + 8 * quad]; \
      bf16x8 b_l = *(const bf16x8*)&Zs_lo[(16 * NB + tx) * LDK + 8 * quad]; \
      C = __builtin_amdgcn_mfma_f32_16x16x32_bf16(a_h, b_h, C, 0, 0, 0); \
      C = __builtin_amdgcn_mfma_f32_16x16x32_bf16(a_h, b_l, C, 0, 0, 0); \
      C = __builtin_amdgcn_mfma_f32_16x16x32_bf16(a_l, b_h, C, 0, 0, 0); }
    DO_NB(0, d0)
    DO_NB(1, d1)
    DO_NB(2, d2)
    DO_NB(3, d3)
    DO_NB(4, d4)
    DO_NB(5, d5)
    DO_NB(6, d6)
    DO_NB(7, d7)
#undef DO_NB
  }

  // Epilogue. C/D layout: col = tx (within nb block), row = 4*quad + reg.
  #pragma unroll
  for (int r = 0; r < 4; ++r) {
    const int row = m0 + 16 * wave + 4 * quad + r;
    const float c2 = cx2[row];
    const float inv = 1.0f / fmaxf(1.0f - c2, 1e-15f);
    const float onec = 1.0f + c2;
    float yv[8];
    #pragma unroll
    for (int nb = 0; nb < 8; ++nb) {
      const float accv = (nb == 0) ? d0[r] : (nb == 1) ? d1[r] : (nb == 2) ? d2[r] :
                         (nb == 3) ? d3[r] : (nb == 4) ? d4[r] : (nb == 5) ? d5[r] :
                         (nb == 6) ? d6[r] : d7[r];
      const int col = mat * DD + n0 + 16 * nb + tx;
      const float znv = zn[col];
      const float u = (2.0f * (accv / znv) * c2r[col] - onec * s2r[col]) * inv;
      const float w = 2.0f * znv * asinhf(u);
      yv[nb] = sinhf(w);
    }
    const int b = row >> 10, s = row & 1023;
    #pragma unroll
    for (int hg = 0; hg < 2; ++hg) {         // two heads per 128-col tile
      float n2 = 0.f;
      #pragma unroll
      for (int j = 0; j < 4; ++j) n2 = fmaf(yv[4*hg+j], yv[4*hg+j], n2);
      n2 = xor_sum16(n2);
      float n = fmaxf(sqrtf(n2), 1e-15f);
      float s1 = (n > MAXN) ? (MAXN / n) : 1.0f;      // project #1
      n2 = n2 * s1 * s1;
      float f = 1.0f / (1.0f + sqrtf(1.0f + n2));     // exp-map scaling
      float fs = s1 * f;
      n2 = n2 * f * f;
      float nb2 = fmaxf(sqrtf(n2), 1e-15f);
      float s2f = (nb2 > MAXN) ? (MAXN / nb2) : 1.0f; // project #2
      fs *= s2f;
      n2 = n2 * s2f * s2f;

      const int head = blockIdx.x * 2 + hg;
      const size_t bh = (size_t)(b * NH + head);
      const size_t outbase = (bh * SS + s) * DH;
      if (mat == 2) {
        const float gamma = 2.0f / fmaxf(1.0f - n2, 1e-15f);
        #pragma unroll
        for (int j = 0; j < 4; ++j)
          OutM[outbase + 16 * j + tx] = yv[4*hg+j] * fs * gamma;
        if (tx == 0) Stat[bh * SS + s] = gamma - 1.0f;
      } else {
        #pragma unroll
        for (int j = 0; j < 4; ++j)
          OutM[outbase + 16 * j + tx] = yv[4*hg+j] * fs;
        if (tx == 0) Stat[bh * SS + s] = n2;
      }
    }
  }
}

// ---------------- K3: fp32 -> split-bf16 (hi/lo) convert; GV also transposed ----------------
__global__ __launch_bounds__(256) void convert_kernel(
    const float* __restrict__ QKV,   // Q,K,GV contiguous, each [bh][s][dh]
    unsigned short* __restrict__ Qhi, unsigned short* __restrict__ Qlo,
    unsigned short* __restrict__ Khi, unsigned short* __restrict__ Klo,
    unsigned short* __restrict__ GThi, unsigned short* __restrict__ GTlo)
{
  const int st = blockIdx.x, bh = blockIdx.y, mat = blockIdx.z;
  const int tid = threadIdx.x;
  const size_t nQKV = (size_t)BB * NH * SS * DH;
  const float* src = QKV + (size_t)mat * nQKV + ((size_t)bh * SS + st * 64) * DH;
  __shared__ unsigned T[64][69];   // packed (lo<<16)|hi, padded stride

  if (mat < 2) {
    unsigned short* dh_ = ((mat == 0) ? Qhi : Khi) + ((size_t)bh * SS + st * 64) * DH;
    unsigned short* dl_ = ((mat == 0) ? Qlo : Klo) + ((size_t)bh * SS + st * 64) * DH;
    #pragma unroll
    for (int i = 0; i < 4; ++i) {
      const int g = tid + 256 * i;
      const int row = g >> 4, c4 = (g & 15) * 4;
      float4 v = *(const float4*)(src + row * DH + c4);
      float a[4] = {v.x, v.y, v.z, v.w};
      ushort4 hv, lv;
      unsigned short* hp = (unsigned short*)&hv;
      unsigned short* lp = (unsigned short*)&lv;
      #pragma unroll
      for (int j = 0; j < 4; ++j) {
        unsigned short hi = f2bf(a[j]);
        hp[j] = hi;
        lp[j] = f2bf(a[j] - bf2f(hi));
      }
      *(ushort4*)(dh_ + row * DH + c4) = hv;
      *(ushort4*)(dl_ + row * DH + c4) = lv;
    }
  } else {
    #pragma unroll
    for (int i = 0; i < 4; ++i) {
      const int g = tid + 256 * i;
      const int row = g >> 4, c4 = (g & 15) * 4;
      float4 v = *(const float4*)(src + row * DH + c4);
      float a[4] = {v.x, v.y, v.z, v.w};
      #pragma unroll
      for (int j = 0; j < 4; ++j) {
        unsigned short hi = f2bf(a[j]);
        unsigned short lo = f2bf(a[j] - bf2f(hi));
        T[row][c4 + j] = ((unsigned)lo << 16) | (unsigned)hi;
      }
    }
    __syncthreads();
    #pragma unroll
    for (int i = 0; i < 4; ++i) {
      const int g = tid + 256 * i;
      const int kb = g & 15, dhr = g >> 4;
      ushort4 hv, lv;
      unsigned short* hp = (unsigned short*)&hv;
      unsigned short* lp = (unsigned short*)&lv;
      #pragma unroll
      for (int j = 0; j < 4; ++j) {
        unsigned u = T[4 * kb + j][dhr];
        hp[j] = (unsigned short)(u & 0xFFFFu);
        lp[j] = (unsigned short)(u >> 16);
      }
      const size_t ob = ((size_t)bh * DH + dhr) * SS + st * 64 + 4 * kb;
      *(ushort4*)(GThi + ob) = hv;
      *(ushort4*)(GTlo + ob) = lv;
    }
  }
}

// ---------------- K4: MFMA flash-style hyperbolic attention ----------------
__global__ __launch_bounds__(256) void flash_attn_kernel(
    const unsigned short* __restrict__ Qhi, const unsigned short* __restrict__ Qlo,
    const unsigned short* __restrict__ Khi, const unsigned short* __restrict__ Klo,
    const unsigned short* __restrict__ GThi, const unsigned short* __restrict__ GTlo,
    const float* __restrict__ q2a, const float* __restrict__ k2a, const float* __restrict__ gm1a,
    const float* __restrict__ mask, float* __restrict__ out)
{
  constexpr int LDK = 72;
  __shared__ unsigned short Ks_hi[64 * LDK];
  __shared__ unsigned short Ks_lo[64 * LDK];
  __shared__ unsigned short Gs_hi[64 * LDK];
  __shared__ unsigned short Gs_lo[64 * LDK];
  __shared__ float k2s[64], ik2s[64], gm1s[64], ems[64];

  const int qt = blockIdx.x, h = blockIdx.y, b = blockIdx.z;
  const int bh = b * NH + h;
  const int tid = threadIdx.x;
  const int wave = tid >> 6, lane = tid & 63;
  const int tx = lane & 15, quad = lane >> 4;
  const int r0 = qt * 64;

  bf16x8 qa_h[2], qa_l[2];
  {
    const size_t qoff = ((size_t)bh * SS + r0 + 16 * wave + tx) * DH;
    #pragma unroll
    for (int kc = 0; kc < 2; ++kc) {
      qa_h[kc] = *(const bf16x8*)(Qhi + qoff + 32 * kc + 8 * quad);
      qa_l[kc] = *(const bf16x8*)(Qlo + qoff + 32 * kc + 8 * quad);
    }
  }
  float q2r[4], iq2[4];
  #pragma unroll
  for (int r = 0; r < 4; ++r) {
    q2r[r] = q2a[(size_t)bh * SS + r0 + 16 * wave + 4 * quad + r];
    iq2[r] = 2.0f / fmaxf(1.0f - q2r[r], 1e-15f);
  }

  const f32x4 zero4 = {0.f, 0.f, 0.f, 0.f};
  f32x4 oacc[4] = {zero4, zero4, zero4, zero4};
  float dden[4] = {0.f, 0.f, 0.f, 0.f};

  const int c0 = tid, c1 = tid + 256;
  const int sr0 = c0 >> 3, sc0 = (c0 & 7) * 8;
  const int sr1 = c1 >> 3, sc1 = (c1 & 7) * 8;

  for (int kt = 0; kt < 16; ++kt) {
    const int t0 = kt * 64;
    __syncthreads();
    {
      const size_t kb_ = ((size_t)bh * SS + t0) * DH;
      const size_t gb_ = (size_t)bh * DH * SS + t0;
      *(uint4*)&Ks_hi[sr0 * LDK + sc0] = *(const uint4*)(Khi + kb_ + (size_t)sr0 * DH + sc0);
      *(uint4*)&Ks_hi[sr1 * LDK + sc1] = *(const uint4*)(Khi + kb_ + (size_t)sr1 * DH + sc1);
      *(uint4*)&Ks_lo[sr0 * LDK + sc0] = *(const uint4*)(Klo + kb_ + (size_t)sr0 * DH + sc0);
      *(uint4*)&Ks_lo[sr1 * LDK + sc1] = *(const uint4*)(Klo + kb_ + (size_t)sr1 * DH + sc1);
      *(uint4*)&Gs_hi[sr0 * LDK + sc0] = *(const uint4*)(GThi + gb_ + (size_t)sr0 * SS + sc0);
      *(uint4*)&Gs_hi[sr1 * LDK + sc1] = *(const uint4*)(GThi + gb_ + (size_t)sr1 * SS + sc1);
      *(uint4*)&Gs_lo[sr0 * LDK + sc0] = *(const uint4*)(GTlo + gb_ + (size_t)sr0 * SS + sc0);
      *(uint4*)&Gs_lo[sr1 * LDK + sc1] = *(const uint4*)(GTlo + gb_ + (size_t)sr1 * SS + sc1);
      if (tid < 64) {
        float k2v = k2a[(size_t)bh * SS + t0 + tid];
        k2s[tid] = k2v;
        ik2s[tid] = 1.0f / fmaxf(1.0f - k2v, 1e-15f);
        gm1s[tid] = gm1a[(size_t)bh * SS + t0 + tid];
        ems[tid] = __expf(mask[(size_t)b * SS + t0 + tid]);
      }
    }
    __syncthreads();

    f32x4 sacc[4] = {zero4, zero4, zero4, zero4};
    #pragma unroll
    for (int kc = 0; kc < 2; ++kc) {
      const int ko = 32 * kc + 8 * quad;
      #pragma unroll
      for (int nb = 0; nb < 4; ++nb) {
        bf16x8 kh = *(const bf16x8*)&Ks_hi[(16 * nb + tx) * LDK + ko];
        bf16x8 kl = *(const bf16x8*)&Ks_lo[(16 * nb + tx) * LDK + ko];
        sacc[nb] = __builtin_amdgcn_mfma_f32_16x16x32_bf16(qa_h[kc], kh, sacc[nb], 0, 0, 0);
        sacc[nb] = __builtin_amdgcn_mfma_f32_16x16x32_bf16(qa_h[kc], kl, sacc[nb], 0, 0, 0);
        sacc[nb] = __builtin_amdgcn_mfma_f32_16x16x32_bf16(qa_l[kc], kh, sacc[nb], 0, 0, 0);
      }
    }

    float pb[4][4];
    #pragma unroll
    for (int nb = 0; nb < 4; ++nb) {
      const int key = 16 * nb + tx;
      const float k2v = k2s[key], ikv = ik2s[key], emv = ems[key], gmv = gm1s[key];
      #pragma unroll
      for (int r = 0; r < 4; ++r) {
        float sv = sacc[nb][r];
        float num = fmaxf(fmaf(-2.0f, sv, q2r[r] + k2v), 1e-15f);
        float e = num * iq2[r] * ikv;
        float g = fmaf(e, e, e + e);
        float z = 1.0f + e + __builtin_amdgcn_sqrtf(g);
        float w = emv * __builtin_amdgcn_rcpf(z);
        pb[r][nb] = w;
        dden[r] = fmaf(w, gmv, dden[r]);
      }
    }
    __syncthreads();

    #pragma unroll
    for (int r = 0; r < 4; ++r) {
      const int prow = 16 * wave + 4 * quad + r;
      #pragma unroll
      for (int nb = 0; nb < 4; ++nb) {
        float w = pb[r][nb];
        unsigned short hi = f2bf(w);
        unsigned short lo = f2bf(w - bf2f(hi));
        Ks_hi[prow * LDK + 16 * nb + tx] = hi;
        Ks_lo[prow * LDK + 16 * nb + tx] = lo;
      }
    }
    #pragma unroll
    for (int kc = 0; kc < 2; ++kc) {
      const int ko = 32 * kc + 8 * quad;
      bf16x8 ph = *(const bf16x8*)&Ks_hi[(16 * wave + tx) * LDK + ko];
      bf16x8 pl = *(const bf16x8*)&Ks_lo[(16 * wave + tx) * LDK + ko];
      #pragma unroll
      for (int nb = 0; nb < 4; ++nb) {
        bf16x8 gh = *(const bf16x8*)&Gs_hi[(16 * nb + tx) * LDK + ko];
        bf16x8 gl = *(const bf16x8*)&Gs_lo[(16 * nb + tx) * LDK + ko];
        oacc[nb] = __builtin_amdgcn_mfma_f32_16x16x32_bf16(ph, gh, oacc[nb], 0, 0, 0);
        oacc[nb] = __builtin_amdgcn_mfma_f32_16x16x32_bf16(ph, gl, oacc[nb], 0, 0, 0);
        oacc[nb] = __builtin_amdgcn_mfma_f32_16x16x32_bf16(pl, gh, oacc[nb], 0, 0, 0);
      }
    }
  }

  #pragma unroll
  for (int r = 0; r < 4; ++r) {
    float d = fmaxf(xor_sum16(dden[r]), 1e-10f);
    float invd = 1.0f / d;
    float tm[4]; float sq = 0.f;
    #pragma unroll
    for (int nb = 0; nb < 4; ++nb) { tm[nb] = oacc[nb][r] * invd; sq = fmaf(tm[nb], tm[nb], sq); }
    sq = xor_sum16(sq);
    const float f = 1.0f / (1.0f + sqrtf(fmaxf(1.0f - sq, 1e-15f)));
    const float n2 = sq * f * f;
    const float n = fmaxf(sqrtf(n2), 1e-15f);
    const float s2 = (n > MAXN) ? (MAXN / n) : 1.0f;
    const float fs = f * s2;
    const int qrow = r0 + 16 * wave + 4 * quad + r;
    #pragma unroll
    for (int nb = 0; nb < 4; ++nb)
      out[((size_t)(b * SS + qrow)) * DD + h * DH + 16 * nb + tx] = tm[nb] * fs;
  }
}

// ---------------- host ----------------
extern "C" void kernel_launch(void* const* d_in, const int* in_sizes, int n_in,
                              void* d_out, int out_size, void* d_ws, size_t ws_size,
                              hipStream_t stream) {
  const float* hs   = (const float*)d_in[0];
  const float* mask = (const float*)d_in[1];
  const float* qz   = (const float*)d_in[2];
  const float* qr   = (const float*)d_in[3];
  const float* kz   = (const float*)d_in[4];
  const float* kr   = (const float*)d_in[5];
  const float* vz   = (const float*)d_in[6];
  const float* vr   = (const float*)d_in[7];
  float* out = (float*)d_out;

  float* ws = (float*)d_ws;
  const size_t nQKV = (size_t)BB * NH * SS * DH;   // 2,097,152
  const size_t nStat = (size_t)BB * NH * SS;       // 32,768
  float* Q   = ws;                   // Q,K,GV must stay contiguous (convert_kernel)
  float* K   = Q + nQKV;
  float* GV  = K + nQKV;
  float* q2  = GV + nQKV;
  float* k2  = q2 + nStat;
  float* gm1 = k2 + nStat;
  float* zn  = gm1 + nStat;          // 3*1024
  float* c2r = zn + 3 * DD;
  float* s2r = c2r + 3 * DD;
  float* cx2 = s2r + 3 * DD;         // 2048
  unsigned short* bbuf = (unsigned short*)(cx2 + 2048);  // 16B-aligned
  unsigned short* Qhi  = bbuf;
  unsigned short* Qlo  = Qhi  + nQKV;
  unsigned short* Khi  = Qlo  + nQKV;
  unsigned short* Klo  = Khi  + nQKV;
  unsigned short* GThi = Klo  + nQKV;
  unsigned short* GTlo = GThi + nQKV;

  // X/ZT split-bf16 buffers alias bbuf: live only BEFORE convert_kernel writes bbuf.
  const size_t nX = (size_t)BB * SS * DD;          // 2,097,152
  const size_t nZ = (size_t)3 * DD * DD;           // 3,145,728
  unsigned short* Xhi  = bbuf;
  unsigned short* Xlo  = Xhi + nX;
  unsigned short* ZThi = Xlo + nX;
  unsigned short* ZTlo = ZThi + nZ;                // total 10.5M shorts <= 12.6M (bbuf)

  col_stats_kernel<<<dim3(16, 3), 256, 0, stream>>>(qz, kz, vz, qr, kr, vr, zn, c2r, s2r);
  row_cx2_kernel<<<dim3(512), 256, 0, stream>>>(hs, cx2);
  convert_x_kernel<<<dim3(1024), 256, 0, stream>>>(hs, Xhi, Xlo);
  convert_zt_kernel<<<dim3(16, 16, 3), 256, 0, stream>>>(qz, kz, vz, ZThi, ZTlo);
  gemm_mfma_kernel<<<dim3(8, 16, 3), 512, 0, stream>>>(
      Xhi, Xlo, ZThi, ZTlo, zn, c2r, s2r, cx2, Q, K, GV, q2, k2, gm1);
  convert_kernel<<<dim3(16, BB * NH, 3), 256, 0, stream>>>(
      Q, Qhi, Qlo, Khi, Klo, GThi, GTlo);
  flash_attn_kernel<<<dim3(16, NH, BB), 256, 0, stream>>>(
      Qhi, Qlo, Khi, Klo, GThi, GTlo, q2, k2, gm1, mask, out);
}

// Round 7
// 256.251 us; speedup vs baseline: 2.4317x; 1.0837x over previous
//
#include <hip/hip_runtime.h>
#include <math.h>

// Problem constants (C = RC = 1)
#define BB 2
#define SS 1024
#define DD 1024
#define NH 16
#define DH 64
#define MAXN 0.996f   // (1 - PROJ_EPS)/RC

typedef __attribute__((ext_vector_type(8))) short bf16x8;  // MFMA A/B frag (4 VGPRs)
typedef __attribute__((ext_vector_type(4))) float f32x4;   // MFMA C/D frag

__device__ __forceinline__ float xor_sum16(float v){
  v += __shfl_xor(v, 1, 64);
  v += __shfl_xor(v, 2, 64);
  v += __shfl_xor(v, 4, 64);
  v += __shfl_xor(v, 8, 64);
  return v;
}

__device__ __forceinline__ unsigned short f2bf(float x){
  unsigned u = __builtin_bit_cast(unsigned, x);
  unsigned r = u + 0x7FFFu + ((u >> 16) & 1u);   // RNE
  return (unsigned short)(r >> 16);
}
__device__ __forceinline__ float bf2f(unsigned short b){
  unsigned u = ((unsigned)b) << 16;
  return __builtin_bit_cast(float, u);
}

// ---------------- K1a: column norms of z + cosh/sinh(2r) ----------------
__global__ __launch_bounds__(256) void col_stats_kernel(
    const float* __restrict__ zq, const float* __restrict__ zk, const float* __restrict__ zv,
    const float* __restrict__ rq, const float* __restrict__ rk, const float* __restrict__ rv,
    float* __restrict__ zn, float* __restrict__ c2r, float* __restrict__ s2r)
{
  const int m = blockIdx.y;
  const float* z = (m == 0) ? zq : ((m == 1) ? zk : zv);
  const float* r = (m == 0) ? rq : ((m == 1) ? rk : rv);
  const int col = blockIdx.x * 64 + (threadIdx.x & 63);
  const int slice = threadIdx.x >> 6;             // 0..3
  float acc = 0.0f;
  for (int i = slice * 256; i < slice * 256 + 256; ++i) {
    float t = z[(size_t)i * DD + col]; acc = fmaf(t, t, acc);
  }
  __shared__ float red[4][64];
  red[slice][threadIdx.x & 63] = acc;
  __syncthreads();
  if (slice == 0) {
    const int c = threadIdx.x & 63;
    float a = red[0][c] + red[1][c] + red[2][c] + red[3][c];
    float n = fmaxf(sqrtf(a), 1e-15f);
    zn[m * DD + col] = n;
    float rr = 2.0f * r[col];
    c2r[m * DD + col] = coshf(rr);
    s2r[m * DD + col] = sinhf(rr);
  }
}

// ---------------- K1b: per-row ||x||^2 ----------------
__global__ __launch_bounds__(256) void row_cx2_kernel(const float* __restrict__ x,
                                                      float* __restrict__ cx2)
{
  const int wave = threadIdx.x >> 6;
  const int lane = threadIdx.x & 63;
  const int row = blockIdx.x * 4 + wave;          // 2048 rows, grid 512
  const float* xr = x + (size_t)row * DD;
  float acc = 0.0f;
  for (int i = lane; i < DD; i += 64) { float t = xr[i]; acc = fmaf(t, t, acc); }
  #pragma unroll
  for (int m = 1; m < 64; m <<= 1) acc += __shfl_xor(acc, m, 64);
  if (lane == 0) cx2[row] = acc;
}

// ---------------- K1c: x -> split-bf16 (hi/lo), row-major [m][k] ----------------
__global__ __launch_bounds__(256) void convert_x_kernel(
    const float* __restrict__ x,
    unsigned short* __restrict__ Xhi, unsigned short* __restrict__ Xlo)
{
  const size_t g0 = ((size_t)blockIdx.x * 256 + threadIdx.x) * 8;
  #pragma unroll
  for (int h = 0; h < 2; ++h) {
    float4 v = *(const float4*)(x + g0 + 4 * h);
    float a[4] = {v.x, v.y, v.z, v.w};
    ushort4 hv, lv;
    unsigned short* hp = (unsigned short*)&hv;
    unsigned short* lp = (unsigned short*)&lv;
    #pragma unroll
    for (int j = 0; j < 4; ++j) {
      unsigned short hi = f2bf(a[j]);
      hp[j] = hi;
      lp[j] = f2bf(a[j] - bf2f(hi));
    }
    *(ushort4*)(Xhi + g0 + 4 * h) = hv;
    *(ushort4*)(Xlo + g0 + 4 * h) = lv;
  }
}

// ---------------- K1d: z -> split-bf16 transposed ZT[mat][n][k] ----------------
__global__ __launch_bounds__(256) void convert_zt_kernel(
    const float* __restrict__ zq, const float* __restrict__ zk, const float* __restrict__ zv,
    unsigned short* __restrict__ ZThi, unsigned short* __restrict__ ZTlo)
{
  const int kt = blockIdx.x, nt = blockIdx.y, mat = blockIdx.z;
  const float* z = (mat == 0) ? zq : ((mat == 1) ? zk : zv);
  const int tid = threadIdx.x;
  __shared__ unsigned T[64][69];   // packed (lo<<16)|hi

  #pragma unroll
  for (int i = 0; i < 4; ++i) {
    const int g = tid + 256 * i;
    const int kr = g >> 4, nc = (g & 15) * 4;
    float4 v = *(const float4*)(z + (size_t)(kt * 64 + kr) * DD + nt * 64 + nc);
    float a[4] = {v.x, v.y, v.z, v.w};
    #pragma unroll
    for (int j = 0; j < 4; ++j) {
      unsigned short hi = f2bf(a[j]);
      unsigned short lo = f2bf(a[j] - bf2f(hi));
      T[kr][nc + j] = ((unsigned)lo << 16) | (unsigned)hi;
    }
  }
  __syncthreads();
  #pragma unroll
  for (int i = 0; i < 4; ++i) {
    const int g = tid + 256 * i;
    const int nr = g >> 4, kc = (g & 15) * 4;
    ushort4 hv, lv;
    unsigned short* hp = (unsigned short*)&hv;
    unsigned short* lp = (unsigned short*)&lv;
    #pragma unroll
    for (int j = 0; j < 4; ++j) {
      unsigned u = T[kc + j][nr];
      hp[j] = (unsigned short)(u & 0xFFFFu);
      lp[j] = (unsigned short)(u >> 16);
    }
    const size_t ob = ((size_t)mat * DD + nt * 64 + nr) * DD + kt * 64 + kc;
    *(ushort4*)(ZThi + ob) = hv;
    *(ushort4*)(ZTlo + ob) = lv;
  }
}

// ---------------- K2: split-bf16 MFMA GEMM (x@z) + Poincare-linear epilogue ----------------
// v4: 64x128 tile, BK=32, 512 threads / 8 waves. Wave (wrow=w&3, wcol=w>>2) owns
// 16 rows x 64 cols = ONE head (epilogue stays wave-local).
// Grid (8 n-tiles, 32 m-tiles, 3 mats) = 768 blocks = exactly 3 blocks/CU:
// round-6's 384-block grid left 1.5 blocks/CU (makespan 2x, Occupancy 24%).
// Register prefetch (round-6 win) retained; acc = 4 named f32x4 (round-5 lesson:
// arrays of f32x4 get demoted to scratch).
__global__ __launch_bounds__(512, 2) void gemm_mfma_kernel(
    const unsigned short* __restrict__ Xhi, const unsigned short* __restrict__ Xlo,
    const unsigned short* __restrict__ ZThi, const unsigned short* __restrict__ ZTlo,
    const float* __restrict__ zn, const float* __restrict__ c2r, const float* __restrict__ s2r,
    const float* __restrict__ cx2,
    float* __restrict__ Q, float* __restrict__ K, float* __restrict__ GV,
    float* __restrict__ q2, float* __restrict__ k2, float* __restrict__ gm1)
{
  constexpr int LDK = 40;                    // halfword stride (80 B), uniform bank use
  __shared__ unsigned short Xs_hi[64 * LDK], Xs_lo[64 * LDK];
  __shared__ unsigned short Zs_hi[128 * LDK], Zs_lo[128 * LDK];

  const int mat = blockIdx.z;
  float* OutM = (mat == 0) ? Q  : ((mat == 1) ? K  : GV);
  float* Stat = (mat == 0) ? q2 : ((mat == 1) ? k2 : gm1);

  const int n0 = blockIdx.x * 128;
  const int m0 = blockIdx.y * 64;
  const int tid = threadIdx.x;
  const int wave = tid >> 6, lane = tid & 63;
  const int tx = lane & 15, quad = lane >> 4;
  const int wrow = wave & 3;                 // rows [16*wrow, +16)
  const int wcol = wave >> 2;                // cols [64*wcol, +64) = head wcol

  // staging: X is 512 uint4 slots (hi then lo), Z is 512 hi + 512 lo; 3 loads/thread
  const bool xhiSel = tid < 256;
  const int xr = (tid & 255) >> 2, xc = (tid & 3) * 8;
  const unsigned short* Xg = (xhiSel ? Xhi : Xlo) + (size_t)(m0 + xr) * DD + xc;
  unsigned short* XsP = (xhiSel ? Xs_hi : Xs_lo) + xr * LDK + xc;
  const int zr = tid >> 2, zc = (tid & 3) * 8;
  const unsigned short* Zgh = ZThi + ((size_t)mat * DD + n0 + zr) * DD + zc;
  const unsigned short* Zgl = ZTlo + ((size_t)mat * DD + n0 + zr) * DD + zc;
  unsigned short* ZsPh = Zs_hi + zr * LDK + zc;
  unsigned short* ZsPl = Zs_lo + zr * LDK + zc;

  const f32x4 z4 = {0.f, 0.f, 0.f, 0.f};
  f32x4 d0 = z4, d1 = z4, d2 = z4, d3 = z4;

  // prologue prefetch (tile 0)
  uint4 pX  = *(const uint4*)(Xg);
  uint4 pZh = *(const uint4*)(Zgh);
  uint4 pZl = *(const uint4*)(Zgl);

  for (int kt = 0; kt < 32; ++kt) {
    __syncthreads();                         // consumers of previous tile done
    *(uint4*)XsP  = pX;
    *(uint4*)ZsPh = pZh;
    *(uint4*)ZsPl = pZl;
    __syncthreads();                         // tile ready
    if (kt < 31) {                           // prefetch kt+1 BEFORE the MFMA phase
      const int k1 = (kt + 1) * 32;
      pX  = *(const uint4*)(Xg + k1);
      pZh = *(const uint4*)(Zgh + k1);
      pZl = *(const uint4*)(Zgl + k1);
    }

    const int arow = 16 * wrow + tx;
    bf16x8 a_h = *(const bf16x8*)&Xs_hi[arow * LDK + 8 * quad];
    bf16x8 a_l = *(const bf16x8*)&Xs_lo[arow * LDK + 8 * quad];

#define DO_NB(NB, C) { \
      const int brow = 16 * (4 * wcol + NB) + tx; \
      bf16x8 b_h = *(const bf16x8*)&Zs_hi[brow * LDK + 8 * quad]; \
      bf16x8 b_l = *(const bf16x8*)&Zs_lo[brow * LDK + 8 * quad]; \
      C = __builtin_amdgcn_mfma_f32_16x16x32_bf16(a_h, b_h, C, 0, 0, 0); \
      C = __builtin_amdgcn_mfma_f32_16x16x32_bf16(a_h, b_l, C, 0, 0, 0); \
      C = __builtin_amdgcn_mfma_f32_16x16x32_bf16(a_l, b_h, C, 0, 0, 0); }
    DO_NB(0, d0)
    DO_NB(1, d1)
    DO_NB(2, d2)
    DO_NB(3, d3)
#undef DO_NB
  }

  // Epilogue. C/D layout: col = tx (within nb), row = 4*quad + reg. One head/wave.
  const int head = blockIdx.x * 2 + wcol;
  #pragma unroll
  for (int r = 0; r < 4; ++r) {
    const int row = m0 + 16 * wrow + 4 * quad + r;
    const float c2 = cx2[row];
    const float inv = 1.0f / fmaxf(1.0f - c2, 1e-15f);
    const float onec = 1.0f + c2;
    float yv[4];
    #pragma unroll
    for (int nb = 0; nb < 4; ++nb) {
      const float accv = (nb == 0) ? d0[r] : (nb == 1) ? d1[r] : (nb == 2) ? d2[r] : d3[r];
      const int col = mat * DD + n0 + 64 * wcol + 16 * nb + tx;
      const float znv = zn[col];
      const float u = (2.0f * (accv / znv) * c2r[col] - onec * s2r[col]) * inv;
      const float w = 2.0f * znv * asinhf(u);
      yv[nb] = sinhf(w);
    }
    const int b = row >> 10, s = row & 1023;
    float n2 = 0.f;
    #pragma unroll
    for (int j = 0; j < 4; ++j) n2 = fmaf(yv[j], yv[j], n2);
    n2 = xor_sum16(n2);
    float n = fmaxf(sqrtf(n2), 1e-15f);
    float s1 = (n > MAXN) ? (MAXN / n) : 1.0f;      // project #1
    n2 = n2 * s1 * s1;
    float f = 1.0f / (1.0f + sqrtf(1.0f + n2));     // exp-map scaling
    float fs = s1 * f;
    n2 = n2 * f * f;
    float nb2 = fmaxf(sqrtf(n2), 1e-15f);
    float s2f = (nb2 > MAXN) ? (MAXN / nb2) : 1.0f; // project #2
    fs *= s2f;
    n2 = n2 * s2f * s2f;

    const size_t bh = (size_t)(b * NH + head);
    const size_t outbase = (bh * SS + s) * DH;
    if (mat == 2) {
      const float gamma = 2.0f / fmaxf(1.0f - n2, 1e-15f);
      #pragma unroll
      for (int j = 0; j < 4; ++j)
        OutM[outbase + 16 * j + tx] = yv[j] * fs * gamma;
      if (tx == 0) Stat[bh * SS + s] = gamma - 1.0f;
    } else {
      #pragma unroll
      for (int j = 0; j < 4; ++j)
        OutM[outbase + 16 * j + tx] = yv[j] * fs;
      if (tx == 0) Stat[bh * SS + s] = n2;
    }
  }
}

// ---------------- K3: fp32 -> split-bf16 (hi/lo) convert; GV also transposed ----------------
__global__ __launch_bounds__(256) void convert_kernel(
    const float* __restrict__ QKV,   // Q,K,GV contiguous, each [bh][s][dh]
    unsigned short* __restrict__ Qhi, unsigned short* __restrict__ Qlo,
    unsigned short* __restrict__ Khi, unsigned short* __restrict__ Klo,
    unsigned short* __restrict__ GThi, unsigned short* __restrict__ GTlo)
{
  const int st = blockIdx.x, bh = blockIdx.y, mat = blockIdx.z;
  const int tid = threadIdx.x;
  const size_t nQKV = (size_t)BB * NH * SS * DH;
  const float* src = QKV + (size_t)mat * nQKV + ((size_t)bh * SS + st * 64) * DH;
  __shared__ unsigned T[64][69];   // packed (lo<<16)|hi, padded stride

  if (mat < 2) {
    unsigned short* dh_ = ((mat == 0) ? Qhi : Khi) + ((size_t)bh * SS + st * 64) * DH;
    unsigned short* dl_ = ((mat == 0) ? Qlo : Klo) + ((size_t)bh * SS + st * 64) * DH;
    #pragma unroll
    for (int i = 0; i < 4; ++i) {
      const int g = tid + 256 * i;
      const int row = g >> 4, c4 = (g & 15) * 4;
      float4 v = *(const float4*)(src + row * DH + c4);
      float a[4] = {v.x, v.y, v.z, v.w};
      ushort4 hv, lv;
      unsigned short* hp = (unsigned short*)&hv;
      unsigned short* lp = (unsigned short*)&lv;
      #pragma unroll
      for (int j = 0; j < 4; ++j) {
        unsigned short hi = f2bf(a[j]);
        hp[j] = hi;
        lp[j] = f2bf(a[j] - bf2f(hi));
      }
      *(ushort4*)(dh_ + row * DH + c4) = hv;
      *(ushort4*)(dl_ + row * DH + c4) = lv;
    }
  } else {
    #pragma unroll
    for (int i = 0; i < 4; ++i) {
      const int g = tid + 256 * i;
      const int row = g >> 4, c4 = (g & 15) * 4;
      float4 v = *(const float4*)(src + row * DH + c4);
      float a[4] = {v.x, v.y, v.z, v.w};
      #pragma unroll
      for (int j = 0; j < 4; ++j) {
        unsigned short hi = f2bf(a[j]);
        unsigned short lo = f2bf(a[j] - bf2f(hi));
        T[row][c4 + j] = ((unsigned)lo << 16) | (unsigned)hi;
      }
    }
    __syncthreads();
    #pragma unroll
    for (int i = 0; i < 4; ++i) {
      const int g = tid + 256 * i;
      const int kb = g & 15, dhr = g >> 4;
      ushort4 hv, lv;
      unsigned short* hp = (unsigned short*)&hv;
      unsigned short* lp = (unsigned short*)&lv;
      #pragma unroll
      for (int j = 0; j < 4; ++j) {
        unsigned u = T[4 * kb + j][dhr];
        hp[j] = (unsigned short)(u & 0xFFFFu);
        lp[j] = (unsigned short)(u >> 16);
      }
      const size_t ob = ((size_t)bh * DH + dhr) * SS + st * 64 + 4 * kb;
      *(ushort4*)(GThi + ob) = hv;
      *(ushort4*)(GTlo + ob) = lv;
    }
  }
}

// ---------------- K4: MFMA flash-style hyperbolic attention ----------------
// v2: register prefetch of the next K/G tile (round-6 gemm win applied here):
// tile kt+1's global loads issue right after the LDS-ready barrier, before the
// QK MFMA + transcendental phase, so the vmcnt drain at the next barrier is hidden.
__global__ __launch_bounds__(256) void flash_attn_kernel(
    const unsigned short* __restrict__ Qhi, const unsigned short* __restrict__ Qlo,
    const unsigned short* __restrict__ Khi, const unsigned short* __restrict__ Klo,
    const unsigned short* __restrict__ GThi, const unsigned short* __restrict__ GTlo,
    const float* __restrict__ q2a, const float* __restrict__ k2a, const float* __restrict__ gm1a,
    const float* __restrict__ mask, float* __restrict__ out)
{
  constexpr int LDK = 72;
  __shared__ unsigned short Ks_hi[64 * LDK];
  __shared__ unsigned short Ks_lo[64 * LDK];
  __shared__ unsigned short Gs_hi[64 * LDK];
  __shared__ unsigned short Gs_lo[64 * LDK];
  __shared__ float k2s[64], ik2s[64], gm1s[64], ems[64];

  const int qt = blockIdx.x, h = blockIdx.y, b = blockIdx.z;
  const int bh = b * NH + h;
  const int tid = threadIdx.x;
  const int wave = tid >> 6, lane = tid & 63;
  const int tx = lane & 15, quad = lane >> 4;
  const int r0 = qt * 64;

  bf16x8 qa_h[2], qa_l[2];
  {
    const size_t qoff = ((size_t)bh * SS + r0 + 16 * wave + tx) * DH;
    #pragma unroll
    for (int kc = 0; kc < 2; ++kc) {
      qa_h[kc] = *(const bf16x8*)(Qhi + qoff + 32 * kc + 8 * quad);
      qa_l[kc] = *(const bf16x8*)(Qlo + qoff + 32 * kc + 8 * quad);
    }
  }
  float q2r[4], iq2[4];
  #pragma unroll
  for (int r = 0; r < 4; ++r) {
    q2r[r] = q2a[(size_t)bh * SS + r0 + 16 * wave + 4 * quad + r];
    iq2[r] = 2.0f / fmaxf(1.0f - q2r[r], 1e-15f);
  }

  const f32x4 zero4 = {0.f, 0.f, 0.f, 0.f};
  f32x4 oacc[4] = {zero4, zero4, zero4, zero4};
  float dden[4] = {0.f, 0.f, 0.f, 0.f};

  const int c0 = tid, c1 = tid + 256;
  const int sr0 = c0 >> 3, sc0 = (c0 & 7) * 8;
  const int sr1 = c1 >> 3, sc1 = (c1 & 7) * 8;

  const size_t kbase = (size_t)bh * SS * DH;
  const size_t gbase = (size_t)bh * DH * SS;

  // prologue prefetch (tile 0)
  uint4 pk_h0 = *(const uint4*)(Khi + kbase + (size_t)sr0 * DH + sc0);
  uint4 pk_h1 = *(const uint4*)(Khi + kbase + (size_t)sr1 * DH + sc1);
  uint4 pk_l0 = *(const uint4*)(Klo + kbase + (size_t)sr0 * DH + sc0);
  uint4 pk_l1 = *(const uint4*)(Klo + kbase + (size_t)sr1 * DH + sc1);
  uint4 pg_h0 = *(const uint4*)(GThi + gbase + (size_t)sr0 * SS + sc0);
  uint4 pg_h1 = *(const uint4*)(GThi + gbase + (size_t)sr1 * SS + sc1);
  uint4 pg_l0 = *(const uint4*)(GTlo + gbase + (size_t)sr0 * SS + sc0);
  uint4 pg_l1 = *(const uint4*)(GTlo + gbase + (size_t)sr1 * SS + sc1);
  float p_k2 = 0.f, p_gm1 = 0.f, p_ms = 0.f;
  if (tid < 64) {
    p_k2  = k2a[(size_t)bh * SS + tid];
    p_gm1 = gm1a[(size_t)bh * SS + tid];
    p_ms  = mask[(size_t)b * SS + tid];
  }

  for (int kt = 0; kt < 16; ++kt) {
    __syncthreads();                         // prev tile fully consumed
    *(uint4*)&Ks_hi[sr0 * LDK + sc0] = pk_h0;
    *(uint4*)&Ks_hi[sr1 * LDK + sc1] = pk_h1;
    *(uint4*)&Ks_lo[sr0 * LDK + sc0] = pk_l0;
    *(uint4*)&Ks_lo[sr1 * LDK + sc1] = pk_l1;
    *(uint4*)&Gs_hi[sr0 * LDK + sc0] = pg_h0;
    *(uint4*)&Gs_hi[sr1 * LDK + sc1] = pg_h1;
    *(uint4*)&Gs_lo[sr0 * LDK + sc0] = pg_l0;
    *(uint4*)&Gs_lo[sr1 * LDK + sc1] = pg_l1;
    if (tid < 64) {
      k2s[tid]  = p_k2;
      ik2s[tid] = 1.0f / fmaxf(1.0f - p_k2, 1e-15f);
      gm1s[tid] = p_gm1;
      ems[tid]  = __expf(p_ms);
    }
    __syncthreads();                         // tile ready
    if (kt < 15) {                           // prefetch kt+1 before the compute phase
      const int t1 = (kt + 1) * 64;
      const size_t kb_ = kbase + (size_t)t1 * DH;
      const size_t gb_ = gbase + t1;
      pk_h0 = *(const uint4*)(Khi + kb_ + (size_t)sr0 * DH + sc0);
      pk_h1 = *(const uint4*)(Khi + kb_ + (size_t)sr1 * DH + sc1);
      pk_l0 = *(const uint4*)(Klo + kb_ + (size_t)sr0 * DH + sc0);
      pk_l1 = *(const uint4*)(Klo + kb_ + (size_t)sr1 * DH + sc1);
      pg_h0 = *(const uint4*)(GThi + gb_ + (size_t)sr0 * SS + sc0);
      pg_h1 = *(const uint4*)(GThi + gb_ + (size_t)sr1 * SS + sc1);
      pg_l0 = *(const uint4*)(GTlo + gb_ + (size_t)sr0 * SS + sc0);
      pg_l1 = *(const uint4*)(GTlo + gb_ + (size_t)sr1 * SS + sc1);
      if (tid < 64) {
        p_k2  = k2a[(size_t)bh * SS + t1 + tid];
        p_gm1 = gm1a[(size_t)bh * SS + t1 + tid];
        p_ms  = mask[(size_t)b * SS + t1 + tid];
      }
    }

    f32x4 sacc[4] = {zero4, zero4, zero4, zero4};
    #pragma unroll
    for (int kc = 0; kc < 2; ++kc) {
      const int ko = 32 * kc + 8 * quad;
      #pragma unroll
      for (int nb = 0; nb < 4; ++nb) {
        bf16x8 kh = *(const bf16x8*)&Ks_hi[(16 * nb + tx) * LDK + ko];
        bf16x8 kl = *(const bf16x8*)&Ks_lo[(16 * nb + tx) * LDK + ko];
        sacc[nb] = __builtin_amdgcn_mfma_f32_16x16x32_bf16(qa_h[kc], kh, sacc[nb], 0, 0, 0);
        sacc[nb] = __builtin_amdgcn_mfma_f32_16x16x32_bf16(qa_h[kc], kl, sacc[nb], 0, 0, 0);
        sacc[nb] = __builtin_amdgcn_mfma_f32_16x16x32_bf16(qa_l[kc], kh, sacc[nb], 0, 0, 0);
      }
    }

    float pb[4][4];
    #pragma unroll
    for (int nb = 0; nb < 4; ++nb) {
      const int key = 16 * nb + tx;
      const float k2v = k2s[key], ikv = ik2s[key], emv = ems[key], gmv = gm1s[key];
      #pragma unroll
      for (int r = 0; r < 4; ++r) {
        float sv = sacc[nb][r];
        float num = fmaxf(fmaf(-2.0f, sv, q2r[r] + k2v), 1e-15f);
        float e = num * iq2[r] * ikv;
        float g = fmaf(e, e, e + e);
        float z = 1.0f + e + __builtin_amdgcn_sqrtf(g);
        float w = emv * __builtin_amdgcn_rcpf(z);
        pb[r][nb] = w;
        dden[r] = fmaf(w, gmv, dden[r]);
      }
    }
    __syncthreads();                         // all waves done reading Ks fragments

    #pragma unroll
    for (int r = 0; r < 4; ++r) {
      const int prow = 16 * wave + 4 * quad + r;
      #pragma unroll
      for (int nb = 0; nb < 4; ++nb) {
        float w = pb[r][nb];
        unsigned short hi = f2bf(w);
        unsigned short lo = f2bf(w - bf2f(hi));
        Ks_hi[prow * LDK + 16 * nb + tx] = hi;
        Ks_lo[prow * LDK + 16 * nb + tx] = lo;
      }
    }
    // PV: same-wave LDS RAW only (rows disjoint per wave) -> no barrier needed
    #pragma unroll
    for (int kc = 0; kc < 2; ++kc) {
      const int ko = 32 * kc + 8 * quad;
      bf16x8 ph = *(const bf16x8*)&Ks_hi[(16 * wave + tx) * LDK + ko];
      bf16x8 pl = *(const bf16x8*)&Ks_lo[(16 * wave + tx) * LDK + ko];
      #pragma unroll
      for (int nb = 0; nb < 4; ++nb) {
        bf16x8 gh = *(const bf16x8*)&Gs_hi[(16 * nb + tx) * LDK + ko];
        bf16x8 gl = *(const bf16x8*)&Gs_lo[(16 * nb + tx) * LDK + ko];
        oacc[nb] = __builtin_amdgcn_mfma_f32_16x16x32_bf16(ph, gh, oacc[nb], 0, 0, 0);
        oacc[nb] = __builtin_amdgcn_mfma_f32_16x16x32_bf16(ph, gl, oacc[nb], 0, 0, 0);
        oacc[nb] = __builtin_amdgcn_mfma_f32_16x16x32_bf16(pl, gh, oacc[nb], 0, 0, 0);
      }
    }
  }

  #pragma unroll
  for (int r = 0; r < 4; ++r) {
    float d = fmaxf(xor_sum16(dden[r]), 1e-10f);
    float invd = 1.0f / d;
    float tm[4]; float sq = 0.f;
    #pragma unroll
    for (int nb = 0; nb < 4; ++nb) { tm[nb] = oacc[nb][r] * invd; sq = fmaf(tm[nb], tm[nb], sq); }
    sq = xor_sum16(sq);
    const float f = 1.0f / (1.0f + sqrtf(fmaxf(1.0f - sq, 1e-15f)));
    const float n2 = sq * f * f;
    const float n = fmaxf(sqrtf(n2), 1e-15f);
    const float s2 = (n > MAXN) ? (MAXN / n) : 1.0f;
    const float fs = f * s2;
    const int qrow = r0 + 16 * wave + 4 * quad + r;
    #pragma unroll
    for (int nb = 0; nb < 4; ++nb)
      out[((size_t)(b * SS + qrow)) * DD + h * DH + 16 * nb + tx] = tm[nb] * fs;
  }
}

// ---------------- host ----------------
extern "C" void kernel_launch(void* const* d_in, const int* in_sizes, int n_in,
                              void* d_out, int out_size, void* d_ws, size_t ws_size,
                              hipStream_t stream) {
  const float* hs   = (const float*)d_in[0];
  const float* mask = (const float*)d_in[1];
  const float* qz   = (const float*)d_in[2];
  const float* qr   = (const float*)d_in[3];
  const float* kz   = (const float*)d_in[4];
  const float* kr   = (const float*)d_in[5];
  const float* vz   = (const float*)d_in[6];
  const float* vr   = (const float*)d_in[7];
  float* out = (float*)d_out;

  float* ws = (float*)d_ws;
  const size_t nQKV = (size_t)BB * NH * SS * DH;   // 2,097,152
  const size_t nStat = (size_t)BB * NH * SS;       // 32,768
  float* Q   = ws;                   // Q,K,GV must stay contiguous (convert_kernel)
  float* K   = Q + nQKV;
  float* GV  = K + nQKV;
  float* q2  = GV + nQKV;
  float* k2  = q2 + nStat;
  float* gm1 = k2 + nStat;
  float* zn  = gm1 + nStat;          // 3*1024
  float* c2r = zn + 3 * DD;
  float* s2r = c2r + 3 * DD;
  float* cx2 = s2r + 3 * DD;         // 2048
  unsigned short* bbuf = (unsigned short*)(cx2 + 2048);  // 16B-aligned
  unsigned short* Qhi  = bbuf;
  unsigned short* Qlo  = Qhi  + nQKV;
  unsigned short* Khi  = Qlo  + nQKV;
  unsigned short* Klo  = Khi  + nQKV;
  unsigned short* GThi = Klo  + nQKV;
  unsigned short* GTlo = GThi + nQKV;

  // X/ZT split-bf16 buffers alias bbuf: live only BEFORE convert_kernel writes bbuf.
  const size_t nX = (size_t)BB * SS * DD;          // 2,097,152
  const size_t nZ = (size_t)3 * DD * DD;           // 3,145,728
  unsigned short* Xhi  = bbuf;
  unsigned short* Xlo  = Xhi + nX;
  unsigned short* ZThi = Xlo + nX;
  unsigned short* ZTlo = ZThi + nZ;                // total 10.5M shorts <= 12.6M (bbuf)

  col_stats_kernel<<<dim3(16, 3), 256, 0, stream>>>(qz, kz, vz, qr, kr, vr, zn, c2r, s2r);
  row_cx2_kernel<<<dim3(512), 256, 0, stream>>>(hs, cx2);
  convert_x_kernel<<<dim3(1024), 256, 0, stream>>>(hs, Xhi, Xlo);
  convert_zt_kernel<<<dim3(16, 16, 3), 256, 0, stream>>>(qz, kz, vz, ZThi, ZTlo);
  gemm_mfma_kernel<<<dim3(8, 32, 3), 512, 0, stream>>>(
      Xhi, Xlo, ZThi, ZTlo, zn, c2r, s2r, cx2, Q, K, GV, q2, k2, gm1);
  convert_kernel<<<dim3(16, BB * NH, 3), 256, 0, stream>>>(
      Q, Qhi, Qlo, Khi, Klo, GThi, GTlo);
  flash_attn_kernel<<<dim3(16, NH, BB), 256, 0, stream>>>(
      Qhi, Qlo, Khi, Klo, GThi, GTlo, q2, k2, gm1, mask, out);
}